// Round 1
// baseline (2798.289 us; speedup 1.0000x reference)
//
#include <hip/hip_runtime.h>
#include <math.h>

#define B_  2
#define N_  2048
#define D_  1024
#define H_  16
#define DH_ 64
#define FF_ 4096
#define M_  (B_ * N_)   // 4096 rows total

// ---------------------------------------------------------------------------
// LayerNorm: one block per row, 256 threads, D=1024 -> one float4 per thread.
// ---------------------------------------------------------------------------
__global__ __launch_bounds__(256) void ln_kernel(const float* __restrict__ x,
                                                 const float* __restrict__ g,
                                                 const float* __restrict__ bta,
                                                 float* __restrict__ y)
{
    const int row = blockIdx.x;
    const int t = threadIdx.x;
    const float4 v = ((const float4*)(x + (size_t)row * D_))[t];
    float s  = v.x + v.y + v.z + v.w;
    float s2 = v.x * v.x + v.y * v.y + v.z * v.z + v.w * v.w;
#pragma unroll
    for (int o = 32; o > 0; o >>= 1) {
        s  += __shfl_down(s, o);
        s2 += __shfl_down(s2, o);
    }
    __shared__ float red[8];
    const int wid = t >> 6;
    if ((t & 63) == 0) { red[wid] = s; red[4 + wid] = s2; }
    __syncthreads();
    if (t == 0) {
        red[0] = red[0] + red[1] + red[2] + red[3];
        red[4] = red[4] + red[5] + red[6] + red[7];
    }
    __syncthreads();
    const float mean = red[0] * (1.0f / D_);
    const float var  = red[4] * (1.0f / D_) - mean * mean;
    const float rstd = rsqrtf(var + 1e-5f);
    const float4 gg = ((const float4*)g)[t];
    const float4 bb = ((const float4*)bta)[t];
    float4 o;
    o.x = (v.x - mean) * rstd * gg.x + bb.x;
    o.y = (v.y - mean) * rstd * gg.y + bb.y;
    o.z = (v.z - mean) * rstd * gg.z + bb.z;
    o.w = (v.w - mean) * rstd * gg.w + bb.w;
    ((float4*)(y + (size_t)row * D_))[t] = o;
}

// ---------------------------------------------------------------------------
// fp32 SGEMM: C(MxN) = A(MxK,row-major) @ B(KxN,row-major) [+ epilogue]
// 128x128 tile, BK=8, 256 threads, 8x8 micro-tile per thread.
// EPI: 0 = none, 1 = +res, 2 = +bias then exact GELU, 3 = +bias +res
// ---------------------------------------------------------------------------
template <int EPI>
__global__ __launch_bounds__(256) void sgemm_kernel(const float* __restrict__ A,
                                                    const float* __restrict__ Bm,
                                                    float* __restrict__ C,
                                                    int M, int Nn, int K,
                                                    const float* __restrict__ bias,
                                                    const float* __restrict__ res)
{
    __shared__ float As[8][128];
    __shared__ float Bs[8][128];
    const int t  = threadIdx.x;
    const int tx = t & 15, ty = t >> 4;
    const int m0 = blockIdx.y * 128, n0 = blockIdx.x * 128;
    const int ar = t >> 1, ak = (t & 1) * 4;   // A: 128 rows x 8 k
    const int br = t >> 5, bc = (t & 31) * 4;  // B: 8 rows x 128 n
    const float* Aptr = A + (size_t)(m0 + ar) * K + ak;
    const float* Bptr = Bm + (size_t)br * Nn + n0 + bc;

    float acc[8][8];
#pragma unroll
    for (int i = 0; i < 8; i++)
#pragma unroll
        for (int j = 0; j < 8; j++) acc[i][j] = 0.f;

    for (int k0 = 0; k0 < K; k0 += 8) {
        const float4 av = *(const float4*)(Aptr + k0);
        const float4 bv = *(const float4*)(Bptr + (size_t)k0 * Nn);
        As[ak + 0][ar] = av.x;
        As[ak + 1][ar] = av.y;
        As[ak + 2][ar] = av.z;
        As[ak + 3][ar] = av.w;
        *(float4*)&Bs[br][bc] = bv;
        __syncthreads();
#pragma unroll
        for (int kk = 0; kk < 8; kk++) {
            float af[8], bf[8];
            *(float4*)&af[0] = *(const float4*)&As[kk][ty * 4];
            *(float4*)&af[4] = *(const float4*)&As[kk][64 + ty * 4];
            *(float4*)&bf[0] = *(const float4*)&Bs[kk][tx * 4];
            *(float4*)&bf[4] = *(const float4*)&Bs[kk][64 + tx * 4];
#pragma unroll
            for (int i = 0; i < 8; i++)
#pragma unroll
                for (int j = 0; j < 8; j++)
                    acc[i][j] = fmaf(af[i], bf[j], acc[i][j]);
        }
        __syncthreads();
    }

    // epilogue + store (two float4 per row-half)
#pragma unroll
    for (int im = 0; im < 2; im++)
#pragma unroll
        for (int ii = 0; ii < 4; ii++) {
            const int i = im * 4 + ii;
            const int row = m0 + im * 64 + ty * 4 + ii;
#pragma unroll
            for (int jm = 0; jm < 2; jm++) {
                const int col = n0 + jm * 64 + tx * 4;
                float vals[4];
#pragma unroll
                for (int jj = 0; jj < 4; jj++) {
                    float val = acc[i][jm * 4 + jj];
                    if (EPI == 2 || EPI == 3) val += bias[col + jj];
                    if (EPI == 1 || EPI == 3) val += res[(size_t)row * Nn + col + jj];
                    if (EPI == 2) val = 0.5f * val * (1.0f + erff(val * 0.70710678118654752f));
                    vals[jj] = val;
                }
                float4 o;
                o.x = vals[0]; o.y = vals[1]; o.z = vals[2]; o.w = vals[3];
                *(float4*)(C + (size_t)row * Nn + col) = o;
            }
        }
}

// ---------------------------------------------------------------------------
// Flash-style fp32 attention (NO 1/sqrt(d) scaling, per reference).
// Q,K,V in (B, N, H*DH) layout == (B, N, H, DH). One block per
// (b, h, 64-row Q tile); streams K/V in 64-row tiles with online softmax.
// 256 threads, thread (ty,tx) owns a 4x4 patch of the 64x64 S / O tiles.
// ---------------------------------------------------------------------------
__global__ __launch_bounds__(256) void attn_kernel(const float* __restrict__ Q,
                                                   const float* __restrict__ K,
                                                   const float* __restrict__ V,
                                                   float* __restrict__ O)
{
    const int qt = blockIdx.x, h = blockIdx.y, b = blockIdx.z;
    const int t = threadIdx.x;
    const int tx = t & 15, ty = t >> 4;
    const size_t hb = (size_t)b * N_ * (H_ * DH_) + (size_t)h * DH_;

    __shared__ float QsT[DH_][68];  // [d][qrow] transposed
    __shared__ float KsT[DH_][68];  // [d][kcol] transposed
    __shared__ float Vs[64][DH_];   // [j][d]
    __shared__ float Ss[64][65];    // scores -> P
    __shared__ float rsS[64];
    __shared__ float lS[64];

    const int q0 = qt * 64;
#pragma unroll
    for (int i = 0; i < 4; i++) {
        const int s = t + i * 256;
        const int row = s >> 4, d4 = (s & 15) * 4;
        const float4 vq = *(const float4*)(Q + hb + (size_t)(q0 + row) * (H_ * DH_) + d4);
        QsT[d4 + 0][row] = vq.x;
        QsT[d4 + 1][row] = vq.y;
        QsT[d4 + 2][row] = vq.z;
        QsT[d4 + 3][row] = vq.w;
    }
    float m_r = -3.0e38f, l_r = 0.f;  // owned by threads 0..63 (row t)
    float acc[4][4] = {{0.f}};
    __syncthreads();

    for (int j0 = 0; j0 < N_; j0 += 64) {
#pragma unroll
        for (int i = 0; i < 4; i++) {
            const int s = t + i * 256;
            const int row = s >> 4, d4 = (s & 15) * 4;
            const float4 vk = *(const float4*)(K + hb + (size_t)(j0 + row) * (H_ * DH_) + d4);
            KsT[d4 + 0][row] = vk.x;
            KsT[d4 + 1][row] = vk.y;
            KsT[d4 + 2][row] = vk.z;
            KsT[d4 + 3][row] = vk.w;
            *(float4*)&Vs[row][d4] =
                *(const float4*)(V + hb + (size_t)(j0 + row) * (H_ * DH_) + d4);
        }
        __syncthreads();

        // S = Q K^T (64x64), 4x4 per thread
        float sc[4][4] = {{0.f}};
#pragma unroll
        for (int d = 0; d < DH_; d++) {
            const float4 a  = *(const float4*)&QsT[d][ty * 4];
            const float4 bv = *(const float4*)&KsT[d][tx * 4];
            sc[0][0] = fmaf(a.x, bv.x, sc[0][0]); sc[0][1] = fmaf(a.x, bv.y, sc[0][1]);
            sc[0][2] = fmaf(a.x, bv.z, sc[0][2]); sc[0][3] = fmaf(a.x, bv.w, sc[0][3]);
            sc[1][0] = fmaf(a.y, bv.x, sc[1][0]); sc[1][1] = fmaf(a.y, bv.y, sc[1][1]);
            sc[1][2] = fmaf(a.y, bv.z, sc[1][2]); sc[1][3] = fmaf(a.y, bv.w, sc[1][3]);
            sc[2][0] = fmaf(a.z, bv.x, sc[2][0]); sc[2][1] = fmaf(a.z, bv.y, sc[2][1]);
            sc[2][2] = fmaf(a.z, bv.z, sc[2][2]); sc[2][3] = fmaf(a.z, bv.w, sc[2][3]);
            sc[3][0] = fmaf(a.w, bv.x, sc[3][0]); sc[3][1] = fmaf(a.w, bv.y, sc[3][1]);
            sc[3][2] = fmaf(a.w, bv.z, sc[3][2]); sc[3][3] = fmaf(a.w, bv.w, sc[3][3]);
        }
#pragma unroll
        for (int i = 0; i < 4; i++) {
            float4 o;
            o.x = sc[i][0]; o.y = sc[i][1]; o.z = sc[i][2]; o.w = sc[i][3];
            *(float4*)&Ss[ty * 4 + i][tx * 4] = o;
        }
        __syncthreads();

        // online softmax update: wave 0, one row per lane
        if (t < 64) {
            float mx = m_r;
#pragma unroll 8
            for (int j = 0; j < 64; j++) mx = fmaxf(mx, Ss[t][j]);
            const float r = expf(m_r - mx);
            float sum = 0.f;
#pragma unroll 8
            for (int j = 0; j < 64; j++) {
                const float p = expf(Ss[t][j] - mx);
                Ss[t][j] = p;
                sum += p;
            }
            l_r = l_r * r + sum;
            m_r = mx;
            rsS[t] = r;
        }
        __syncthreads();

        // rescale O, then O += P @ V
        float rr[4];
#pragma unroll
        for (int i = 0; i < 4; i++) rr[i] = rsS[ty * 4 + i];
#pragma unroll
        for (int i = 0; i < 4; i++)
#pragma unroll
            for (int j = 0; j < 4; j++) acc[i][j] *= rr[i];

#pragma unroll 8
        for (int j = 0; j < 64; j++) {
            const float4 vv = *(const float4*)&Vs[j][tx * 4];
            const float p0 = Ss[ty * 4 + 0][j];
            const float p1 = Ss[ty * 4 + 1][j];
            const float p2 = Ss[ty * 4 + 2][j];
            const float p3 = Ss[ty * 4 + 3][j];
            acc[0][0] = fmaf(p0, vv.x, acc[0][0]); acc[0][1] = fmaf(p0, vv.y, acc[0][1]);
            acc[0][2] = fmaf(p0, vv.z, acc[0][2]); acc[0][3] = fmaf(p0, vv.w, acc[0][3]);
            acc[1][0] = fmaf(p1, vv.x, acc[1][0]); acc[1][1] = fmaf(p1, vv.y, acc[1][1]);
            acc[1][2] = fmaf(p1, vv.z, acc[1][2]); acc[1][3] = fmaf(p1, vv.w, acc[1][3]);
            acc[2][0] = fmaf(p2, vv.x, acc[2][0]); acc[2][1] = fmaf(p2, vv.y, acc[2][1]);
            acc[2][2] = fmaf(p2, vv.z, acc[2][2]); acc[2][3] = fmaf(p2, vv.w, acc[2][3]);
            acc[3][0] = fmaf(p3, vv.x, acc[3][0]); acc[3][1] = fmaf(p3, vv.y, acc[3][1]);
            acc[3][2] = fmaf(p3, vv.z, acc[3][2]); acc[3][3] = fmaf(p3, vv.w, acc[3][3]);
        }
        __syncthreads();
    }

    if (t < 64) lS[t] = l_r;
    __syncthreads();
#pragma unroll
    for (int i = 0; i < 4; i++) {
        const int row = q0 + ty * 4 + i;
        const float inv = 1.f / lS[ty * 4 + i];
        float4 o;
        o.x = acc[i][0] * inv; o.y = acc[i][1] * inv;
        o.z = acc[i][2] * inv; o.w = acc[i][3] * inv;
        *(float4*)(O + hb + (size_t)row * (H_ * DH_) + tx * 4) = o;
    }
}

// ---------------------------------------------------------------------------
extern "C" void kernel_launch(void* const* d_in, const int* in_sizes, int n_in,
                              void* d_out, int out_size, void* d_ws, size_t ws_size,
                              hipStream_t stream)
{
    const float* x     = (const float*)d_in[0];
    const float* wq    = (const float*)d_in[1];
    const float* wk    = (const float*)d_in[2];
    const float* wv    = (const float*)d_in[3];
    const float* wo    = (const float*)d_in[4];
    const float* w1    = (const float*)d_in[5];
    const float* b1    = (const float*)d_in[6];
    const float* w2    = (const float*)d_in[7];
    const float* b2    = (const float*)d_in[8];
    const float* ln1_g = (const float*)d_in[9];
    const float* ln1_b = (const float*)d_in[10];
    const float* ln2_g = (const float*)d_in[11];
    const float* ln2_b = (const float*)d_in[12];

    const size_t MD = (size_t)M_ * D_;       // 4 194 304 floats
    float* ws = (float*)d_ws;
    float* h   = ws;            // LN1 output; later reused for attention output
    float* qb  = h + MD;        // Q proj; later reused for LN2 output
    float* kb  = qb + MD;
    float* vb  = kb + MD;
    float* x1  = vb + MD;       // residual after attention
    float* ff  = x1 + MD;       // M_ x FF_  (67 MB)
    // total: 5*MD + M_*FF_ floats = 151 MB

    // 1. h = LN1(x)
    ln_kernel<<<M_, 256, 0, stream>>>(x, ln1_g, ln1_b, h);

    // 2. Q/K/V projections (plain GEMM, output in (B,N,H*DH) layout)
    dim3 gQKV(D_ / 128, M_ / 128);
    sgemm_kernel<0><<<gQKV, 256, 0, stream>>>(h, wq, qb, M_, D_, D_, nullptr, nullptr);
    sgemm_kernel<0><<<gQKV, 256, 0, stream>>>(h, wk, kb, M_, D_, D_, nullptr, nullptr);
    sgemm_kernel<0><<<gQKV, 256, 0, stream>>>(h, wv, vb, M_, D_, D_, nullptr, nullptr);

    // 3. attention -> reuse h as attention output
    dim3 gA(N_ / 64, H_, B_);
    attn_kernel<<<gA, 256, 0, stream>>>(qb, kb, vb, h);

    // 4. x1 = attn_out @ wo + x
    sgemm_kernel<1><<<gQKV, 256, 0, stream>>>(h, wo, x1, M_, D_, D_, nullptr, x);

    // 5. h2 = LN2(x1) -> reuse qb
    ln_kernel<<<M_, 256, 0, stream>>>(x1, ln2_g, ln2_b, qb);

    // 6. ff = GELU(h2 @ w1 + b1)
    dim3 gFF1(FF_ / 128, M_ / 128);
    sgemm_kernel<2><<<gFF1, 256, 0, stream>>>(qb, w1, ff, M_, FF_, D_, b1, nullptr);

    // 7. out = ff @ w2 + b2 + x1
    dim3 gFF2(D_ / 128, M_ / 128);
    sgemm_kernel<3><<<gFF2, 256, 0, stream>>>(ff, w2, (float*)d_out, M_, D_, FF_, b2, x1);
}

// Round 2
// 1273.189 us; speedup vs baseline: 2.1979x; 2.1979x over previous
//
#include <hip/hip_runtime.h>
#include <math.h>
#include <stdint.h>

#define B_  2
#define N_  2048
#define D_  1024
#define H_  16
#define DH_ 64
#define FF_ 4096
#define M_  (B_ * N_)   // 4096 rows total

typedef __bf16 bf16;
typedef float  f32x4  __attribute__((ext_vector_type(4)));
typedef __bf16 bf16x8 __attribute__((ext_vector_type(8)));
typedef __bf16 bf16x4 __attribute__((ext_vector_type(4)));

// async global->LDS, 16B per lane; LDS dest = wave-uniform base + lane*16
__device__ __forceinline__ void async_copy16(const void* g, void* l) {
    __builtin_amdgcn_global_load_lds((__attribute__((address_space(1))) unsigned int*)g,
                                     (__attribute__((address_space(3))) unsigned int*)l,
                                     16, 0, 0);
}

// ---------------------------------------------------------------------------
// LayerNorm: one block per row, 256 threads, D=1024. fp32 in, bf16 out.
// ---------------------------------------------------------------------------
__global__ __launch_bounds__(256) void ln_kernel(const float* __restrict__ x,
                                                 const float* __restrict__ g,
                                                 const float* __restrict__ bta,
                                                 bf16* __restrict__ y)
{
    const int row = blockIdx.x;
    const int t = threadIdx.x;
    const float4 v = ((const float4*)(x + (size_t)row * D_))[t];
    float s  = v.x + v.y + v.z + v.w;
    float s2 = v.x * v.x + v.y * v.y + v.z * v.z + v.w * v.w;
#pragma unroll
    for (int o = 32; o > 0; o >>= 1) {
        s  += __shfl_down(s, o);
        s2 += __shfl_down(s2, o);
    }
    __shared__ float red[8];
    const int wid = t >> 6;
    if ((t & 63) == 0) { red[wid] = s; red[4 + wid] = s2; }
    __syncthreads();
    if (t == 0) {
        red[0] = red[0] + red[1] + red[2] + red[3];
        red[4] = red[4] + red[5] + red[6] + red[7];
    }
    __syncthreads();
    const float mean = red[0] * (1.0f / D_);
    const float var  = red[4] * (1.0f / D_) - mean * mean;
    const float rstd = rsqrtf(var + 1e-5f);
    const float4 gg = ((const float4*)g)[t];
    const float4 bb = ((const float4*)bta)[t];
    bf16x4 o;
    o[0] = (bf16)((v.x - mean) * rstd * gg.x + bb.x);
    o[1] = (bf16)((v.y - mean) * rstd * gg.y + bb.y);
    o[2] = (bf16)((v.z - mean) * rstd * gg.z + bb.z);
    o[3] = (bf16)((v.w - mean) * rstd * gg.w + bb.w);
    ((bf16x4*)(y + (size_t)row * D_))[t] = o;
}

// ---------------------------------------------------------------------------
// fp32 [R][C] -> bf16 [C][R] transpose (weights: done once per launch).
// ---------------------------------------------------------------------------
__global__ __launch_bounds__(256) void transpose_bf16(const float* __restrict__ in,
                                                      bf16* __restrict__ out,
                                                      int R, int C)
{
    __shared__ float tile[32][33];
    const int c0 = blockIdx.x * 32, r0 = blockIdx.y * 32;
    const int tx = threadIdx.x, ty = threadIdx.y;  // (32,8)
#pragma unroll
    for (int i = 0; i < 4; i++)
        tile[ty + i * 8][tx] = in[(size_t)(r0 + ty + i * 8) * C + c0 + tx];
    __syncthreads();
#pragma unroll
    for (int i = 0; i < 4; i++)
        out[(size_t)(c0 + ty + i * 8) * R + r0 + tx] = (bf16)tile[tx][ty + i * 8];
}

// ---------------------------------------------------------------------------
// bf16 MFMA GEMM (m97 structure): C(MxN) = A(MxK) @ Bt(NxK)^T
// 128x128 tile, BK=32, 256 threads (4 waves, 2x2), 16x16x32 MFMA,
// global_load_lds width-16 staging, single LDS buffer, 2 barriers/K-step.
// EPI: 0 none | 1 +res | 2 +bias,GELU | 3 +bias,+res.  OUTBF16 casts store.
// All dims assumed multiples of 128 (tile) / 32 (BK) -- true for this layer.
// ---------------------------------------------------------------------------
template <int EPI, bool OUTBF16>
__global__ __launch_bounds__(256) void mfma_gemm(const bf16* __restrict__ A,
                                                 const bf16* __restrict__ Bt,
                                                 void* __restrict__ Cout,
                                                 int M, int N, int K,
                                                 const float* __restrict__ bias,
                                                 const float* __restrict__ res)
{
    __shared__ bf16 As[128 * 32];
    __shared__ bf16 Bs[128 * 32];
    const int t = threadIdx.x;
    const int w = t >> 6, lane = t & 63;
    const int wr = w >> 1, wc = w & 1;          // wave -> 64x64 quadrant
    const int m0 = blockIdx.y * 128, n0 = blockIdx.x * 128;
    const int lr = lane & 15, lg = lane >> 4;   // MFMA fragment coords

    f32x4 acc[4][4];
#pragma unroll
    for (int m = 0; m < 4; m++)
#pragma unroll
        for (int n = 0; n < 4; n++) acc[m][n] = {0.f, 0.f, 0.f, 0.f};

    // staging geometry: 8 chunks of 1KB per 8KB tile; wave w owns chunks 2w,2w+1
    const int q0c = w * 2, q1c = w * 2 + 1;
    const int row0 = q0c * 16 + (lane >> 2);
    const int row1 = q1c * 16 + (lane >> 2);
    const int kk = (lane & 3) * 8;

    for (int k0 = 0; k0 < K; k0 += 32) {
        async_copy16(A  + (size_t)(m0 + row0) * K + k0 + kk, &As[q0c * 512]);
        async_copy16(A  + (size_t)(m0 + row1) * K + k0 + kk, &As[q1c * 512]);
        async_copy16(Bt + (size_t)(n0 + row0) * K + k0 + kk, &Bs[q0c * 512]);
        async_copy16(Bt + (size_t)(n0 + row1) * K + k0 + kk, &Bs[q1c * 512]);
        __syncthreads();   // drains vmcnt (incl. LDS writes) then barrier

        bf16x8 af[4], bfr[4];
#pragma unroll
        for (int m = 0; m < 4; m++)
            af[m] = *(const bf16x8*)&As[(wr * 64 + m * 16 + lr) * 32 + lg * 8];
#pragma unroll
        for (int n = 0; n < 4; n++)
            bfr[n] = *(const bf16x8*)&Bs[(wc * 64 + n * 16 + lr) * 32 + lg * 8];
#pragma unroll
        for (int m = 0; m < 4; m++)
#pragma unroll
            for (int n = 0; n < 4; n++)
                acc[m][n] = __builtin_amdgcn_mfma_f32_16x16x32_bf16(
                    af[m], bfr[n], acc[m][n], 0, 0, 0);
        __syncthreads();
    }

    // epilogue: C/D layout col=lane&15, row=(lane>>4)*4+reg  [m89-verified]
#pragma unroll
    for (int m = 0; m < 4; m++)
#pragma unroll
        for (int n = 0; n < 4; n++) {
            const int col = n0 + wc * 64 + n * 16 + lr;
            const float bv = (EPI >= 2) ? bias[col] : 0.f;
#pragma unroll
            for (int r2 = 0; r2 < 4; r2++) {
                const int row = m0 + wr * 64 + m * 16 + lg * 4 + r2;
                float v = acc[m][n][r2] + bv;
                if (EPI == 1 || EPI == 3) v += res[(size_t)row * N + col];
                if (EPI == 2) v = 0.5f * v * (1.0f + erff(v * 0.70710678118654752f));
                if (OUTBF16) ((bf16*)Cout)[(size_t)row * N + col] = (bf16)v;
                else         ((float*)Cout)[(size_t)row * N + col] = v;
            }
        }
}

// ---------------------------------------------------------------------------
// Flash-style fp32 attention (unchanged from passing baseline except bf16 out).
// NO 1/sqrt(d) scaling, per reference. One block per (b, h, 64-row Q tile).
// ---------------------------------------------------------------------------
__global__ __launch_bounds__(256) void attn_kernel(const float* __restrict__ Q,
                                                   const float* __restrict__ K,
                                                   const float* __restrict__ V,
                                                   bf16* __restrict__ O)
{
    const int qt = blockIdx.x, h = blockIdx.y, b = blockIdx.z;
    const int t = threadIdx.x;
    const int tx = t & 15, ty = t >> 4;
    const size_t hb = (size_t)b * N_ * (H_ * DH_) + (size_t)h * DH_;

    __shared__ float QsT[DH_][68];
    __shared__ float KsT[DH_][68];
    __shared__ float Vs[64][DH_];
    __shared__ float Ss[64][65];
    __shared__ float rsS[64];
    __shared__ float lS[64];

    const int q0 = qt * 64;
#pragma unroll
    for (int i = 0; i < 4; i++) {
        const int s = t + i * 256;
        const int row = s >> 4, d4 = (s & 15) * 4;
        const float4 vq = *(const float4*)(Q + hb + (size_t)(q0 + row) * (H_ * DH_) + d4);
        QsT[d4 + 0][row] = vq.x;
        QsT[d4 + 1][row] = vq.y;
        QsT[d4 + 2][row] = vq.z;
        QsT[d4 + 3][row] = vq.w;
    }
    float m_r = -3.0e38f, l_r = 0.f;
    float acc[4][4] = {{0.f}};
    __syncthreads();

    for (int j0 = 0; j0 < N_; j0 += 64) {
#pragma unroll
        for (int i = 0; i < 4; i++) {
            const int s = t + i * 256;
            const int row = s >> 4, d4 = (s & 15) * 4;
            const float4 vk = *(const float4*)(K + hb + (size_t)(j0 + row) * (H_ * DH_) + d4);
            KsT[d4 + 0][row] = vk.x;
            KsT[d4 + 1][row] = vk.y;
            KsT[d4 + 2][row] = vk.z;
            KsT[d4 + 3][row] = vk.w;
            *(float4*)&Vs[row][d4] =
                *(const float4*)(V + hb + (size_t)(j0 + row) * (H_ * DH_) + d4);
        }
        __syncthreads();

        float sc[4][4] = {{0.f}};
#pragma unroll
        for (int d = 0; d < DH_; d++) {
            const float4 a  = *(const float4*)&QsT[d][ty * 4];
            const float4 bv = *(const float4*)&KsT[d][tx * 4];
            sc[0][0] = fmaf(a.x, bv.x, sc[0][0]); sc[0][1] = fmaf(a.x, bv.y, sc[0][1]);
            sc[0][2] = fmaf(a.x, bv.z, sc[0][2]); sc[0][3] = fmaf(a.x, bv.w, sc[0][3]);
            sc[1][0] = fmaf(a.y, bv.x, sc[1][0]); sc[1][1] = fmaf(a.y, bv.y, sc[1][1]);
            sc[1][2] = fmaf(a.y, bv.z, sc[1][2]); sc[1][3] = fmaf(a.y, bv.w, sc[1][3]);
            sc[2][0] = fmaf(a.z, bv.x, sc[2][0]); sc[2][1] = fmaf(a.z, bv.y, sc[2][1]);
            sc[2][2] = fmaf(a.z, bv.z, sc[2][2]); sc[2][3] = fmaf(a.z, bv.w, sc[2][3]);
            sc[3][0] = fmaf(a.w, bv.x, sc[3][0]); sc[3][1] = fmaf(a.w, bv.y, sc[3][1]);
            sc[3][2] = fmaf(a.w, bv.z, sc[3][2]); sc[3][3] = fmaf(a.w, bv.w, sc[3][3]);
        }
#pragma unroll
        for (int i = 0; i < 4; i++) {
            float4 o;
            o.x = sc[i][0]; o.y = sc[i][1]; o.z = sc[i][2]; o.w = sc[i][3];
            *(float4*)&Ss[ty * 4 + i][tx * 4] = o;
        }
        __syncthreads();

        if (t < 64) {
            float mx = m_r;
#pragma unroll 8
            for (int j = 0; j < 64; j++) mx = fmaxf(mx, Ss[t][j]);
            const float r = expf(m_r - mx);
            float sum = 0.f;
#pragma unroll 8
            for (int j = 0; j < 64; j++) {
                const float p = expf(Ss[t][j] - mx);
                Ss[t][j] = p;
                sum += p;
            }
            l_r = l_r * r + sum;
            m_r = mx;
            rsS[t] = r;
        }
        __syncthreads();

        float rr[4];
#pragma unroll
        for (int i = 0; i < 4; i++) rr[i] = rsS[ty * 4 + i];
#pragma unroll
        for (int i = 0; i < 4; i++)
#pragma unroll
            for (int j = 0; j < 4; j++) acc[i][j] *= rr[i];

#pragma unroll 8
        for (int j = 0; j < 64; j++) {
            const float4 vv = *(const float4*)&Vs[j][tx * 4];
            const float p0 = Ss[ty * 4 + 0][j];
            const float p1 = Ss[ty * 4 + 1][j];
            const float p2 = Ss[ty * 4 + 2][j];
            const float p3 = Ss[ty * 4 + 3][j];
            acc[0][0] = fmaf(p0, vv.x, acc[0][0]); acc[0][1] = fmaf(p0, vv.y, acc[0][1]);
            acc[0][2] = fmaf(p0, vv.z, acc[0][2]); acc[0][3] = fmaf(p0, vv.w, acc[0][3]);
            acc[1][0] = fmaf(p1, vv.x, acc[1][0]); acc[1][1] = fmaf(p1, vv.y, acc[1][1]);
            acc[1][2] = fmaf(p1, vv.z, acc[1][2]); acc[1][3] = fmaf(p1, vv.w, acc[1][3]);
            acc[2][0] = fmaf(p2, vv.x, acc[2][0]); acc[2][1] = fmaf(p2, vv.y, acc[2][1]);
            acc[2][2] = fmaf(p2, vv.z, acc[2][2]); acc[2][3] = fmaf(p2, vv.w, acc[2][3]);
            acc[3][0] = fmaf(p3, vv.x, acc[3][0]); acc[3][1] = fmaf(p3, vv.y, acc[3][1]);
            acc[3][2] = fmaf(p3, vv.z, acc[3][2]); acc[3][3] = fmaf(p3, vv.w, acc[3][3]);
        }
        __syncthreads();
    }

    if (t < 64) lS[t] = l_r;
    __syncthreads();
#pragma unroll
    for (int i = 0; i < 4; i++) {
        const int row = q0 + ty * 4 + i;
        const float inv = 1.f / lS[ty * 4 + i];
        bf16x4 o4;
        o4[0] = (bf16)(acc[i][0] * inv);
        o4[1] = (bf16)(acc[i][1] * inv);
        o4[2] = (bf16)(acc[i][2] * inv);
        o4[3] = (bf16)(acc[i][3] * inv);
        *(bf16x4*)(O + hb + (size_t)row * (H_ * DH_) + tx * 4) = o4;
    }
}

// ---------------------------------------------------------------------------
extern "C" void kernel_launch(void* const* d_in, const int* in_sizes, int n_in,
                              void* d_out, int out_size, void* d_ws, size_t ws_size,
                              hipStream_t stream)
{
    const float* x     = (const float*)d_in[0];
    const float* wq    = (const float*)d_in[1];
    const float* wk    = (const float*)d_in[2];
    const float* wv    = (const float*)d_in[3];
    const float* wo    = (const float*)d_in[4];
    const float* w1    = (const float*)d_in[5];
    const float* b1    = (const float*)d_in[6];
    const float* w2    = (const float*)d_in[7];
    const float* b2    = (const float*)d_in[8];
    const float* ln1_g = (const float*)d_in[9];
    const float* ln1_b = (const float*)d_in[10];
    const float* ln2_g = (const float*)d_in[11];
    const float* ln2_b = (const float*)d_in[12];

    const size_t MD = (size_t)M_ * D_;
    char* wsb = (char*)d_ws;
    auto alloc = [&](size_t bytes) { char* p = wsb; wsb += (bytes + 255) & ~(size_t)255; return p; };
    bf16*  hb  = (bf16*)alloc(MD * 2);                 // LN1 out
    float* qb  = (float*)alloc(MD * 4);
    float* kb  = (float*)alloc(MD * 4);
    float* vb  = (float*)alloc(MD * 4);
    bf16*  ab  = (bf16*)alloc(MD * 2);                 // attn out
    float* x1  = (float*)alloc(MD * 4);                // residual after attn
    bf16*  h2b = (bf16*)alloc(MD * 2);                 // LN2 out
    bf16*  ffb = (bf16*)alloc((size_t)M_ * FF_ * 2);   // GELU out
    bf16*  wqT = (bf16*)alloc((size_t)D_ * D_ * 2);
    bf16*  wkT = (bf16*)alloc((size_t)D_ * D_ * 2);
    bf16*  wvT = (bf16*)alloc((size_t)D_ * D_ * 2);
    bf16*  woT = (bf16*)alloc((size_t)D_ * D_ * 2);
    bf16*  w1T = (bf16*)alloc((size_t)D_ * FF_ * 2);
    bf16*  w2T = (bf16*)alloc((size_t)FF_ * D_ * 2);

    // weight cast+transpose to (N x K) bf16
    dim3 tb(32, 8);
    transpose_bf16<<<dim3(D_ / 32, D_ / 32), tb, 0, stream>>>(wq, wqT, D_, D_);
    transpose_bf16<<<dim3(D_ / 32, D_ / 32), tb, 0, stream>>>(wk, wkT, D_, D_);
    transpose_bf16<<<dim3(D_ / 32, D_ / 32), tb, 0, stream>>>(wv, wvT, D_, D_);
    transpose_bf16<<<dim3(D_ / 32, D_ / 32), tb, 0, stream>>>(wo, woT, D_, D_);
    transpose_bf16<<<dim3(FF_ / 32, D_ / 32), tb, 0, stream>>>(w1, w1T, D_, FF_);
    transpose_bf16<<<dim3(D_ / 32, FF_ / 32), tb, 0, stream>>>(w2, w2T, FF_, D_);

    // 1. LN1
    ln_kernel<<<M_, 256, 0, stream>>>(x, ln1_g, ln1_b, hb);

    // 2. QKV projections (fp32 out for the fp32 attention kernel)
    dim3 gP(D_ / 128, M_ / 128);
    mfma_gemm<0, false><<<gP, 256, 0, stream>>>(hb, wqT, qb, M_, D_, D_, nullptr, nullptr);
    mfma_gemm<0, false><<<gP, 256, 0, stream>>>(hb, wkT, kb, M_, D_, D_, nullptr, nullptr);
    mfma_gemm<0, false><<<gP, 256, 0, stream>>>(hb, wvT, vb, M_, D_, D_, nullptr, nullptr);

    // 3. attention (bf16 out)
    attn_kernel<<<dim3(N_ / 64, H_, B_), 256, 0, stream>>>(qb, kb, vb, ab);

    // 4. x1 = attn @ wo + x
    mfma_gemm<1, false><<<gP, 256, 0, stream>>>(ab, woT, x1, M_, D_, D_, nullptr, x);

    // 5. LN2
    ln_kernel<<<M_, 256, 0, stream>>>(x1, ln2_g, ln2_b, h2b);

    // 6. ff = GELU(h2 @ w1 + b1)  (bf16 out)
    mfma_gemm<2, true><<<dim3(FF_ / 128, M_ / 128), 256, 0, stream>>>(
        h2b, w1T, ffb, M_, FF_, D_, b1, nullptr);

    // 7. out = ff @ w2 + b2 + x1  (fp32 out)
    mfma_gemm<3, false><<<gP, 256, 0, stream>>>(ffb, w2T, (float*)d_out, M_, D_, FF_, b2, x1);
}

// Round 5
// 537.331 us; speedup vs baseline: 5.2078x; 2.3695x over previous
//
#include <hip/hip_runtime.h>
#include <math.h>
#include <stdint.h>

#define B_  2
#define N_  2048
#define D_  1024
#define H_  16
#define DH_ 64
#define FF_ 4096
#define M_  (B_ * N_)   // 4096 rows total

typedef __bf16 bf16;
typedef float  f32x4  __attribute__((ext_vector_type(4)));
typedef __bf16 bf16x8 __attribute__((ext_vector_type(8)));
typedef __bf16 bf16x4 __attribute__((ext_vector_type(4)));

// async global->LDS, 16B per lane; LDS dest = wave-uniform base + lane*16
__device__ __forceinline__ void async_copy16(const void* g, void* l) {
    __builtin_amdgcn_global_load_lds((__attribute__((address_space(1))) unsigned int*)g,
                                     (__attribute__((address_space(3))) unsigned int*)l,
                                     16, 0, 0);
}

// ---------------------------------------------------------------------------
// LayerNorm: one block per row, 256 threads, D=1024. fp32 in, bf16 out.
// ---------------------------------------------------------------------------
__global__ __launch_bounds__(256) void ln_kernel(const float* __restrict__ x,
                                                 const float* __restrict__ g,
                                                 const float* __restrict__ bta,
                                                 bf16* __restrict__ y)
{
    const int row = blockIdx.x;
    const int t = threadIdx.x;
    const float4 v = ((const float4*)(x + (size_t)row * D_))[t];
    float s  = v.x + v.y + v.z + v.w;
    float s2 = v.x * v.x + v.y * v.y + v.z * v.z + v.w * v.w;
#pragma unroll
    for (int o = 32; o > 0; o >>= 1) {
        s  += __shfl_down(s, o);
        s2 += __shfl_down(s2, o);
    }
    __shared__ float red[8];
    const int wid = t >> 6;
    if ((t & 63) == 0) { red[wid] = s; red[4 + wid] = s2; }
    __syncthreads();
    if (t == 0) {
        red[0] = red[0] + red[1] + red[2] + red[3];
        red[4] = red[4] + red[5] + red[6] + red[7];
    }
    __syncthreads();
    const float mean = red[0] * (1.0f / D_);
    const float var  = red[4] * (1.0f / D_) - mean * mean;
    const float rstd = rsqrtf(var + 1e-5f);
    const float4 gg = ((const float4*)g)[t];
    const float4 bb = ((const float4*)bta)[t];
    bf16x4 o;
    o[0] = (bf16)((v.x - mean) * rstd * gg.x + bb.x);
    o[1] = (bf16)((v.y - mean) * rstd * gg.y + bb.y);
    o[2] = (bf16)((v.z - mean) * rstd * gg.z + bb.z);
    o[3] = (bf16)((v.w - mean) * rstd * gg.w + bb.w);
    ((bf16x4*)(y + (size_t)row * D_))[t] = o;
}

// ---------------------------------------------------------------------------
// fp32 [R][C] -> bf16 [C][R] transpose (weights: done once per launch).
// ---------------------------------------------------------------------------
__global__ __launch_bounds__(256) void transpose_bf16(const float* __restrict__ in,
                                                      bf16* __restrict__ out,
                                                      int R, int C)
{
    __shared__ float tile[32][33];
    const int c0 = blockIdx.x * 32, r0 = blockIdx.y * 32;
    const int tx = threadIdx.x, ty = threadIdx.y;  // (32,8)
#pragma unroll
    for (int i = 0; i < 4; i++)
        tile[ty + i * 8][tx] = in[(size_t)(r0 + ty + i * 8) * C + c0 + tx];
    __syncthreads();
#pragma unroll
    for (int i = 0; i < 4; i++)
        out[(size_t)(c0 + ty + i * 8) * R + r0 + tx] = (bf16)tile[tx][ty + i * 8];
}

// ---------------------------------------------------------------------------
// bf16 MFMA GEMM (m97 structure): C(MxN) = A(MxK) @ Bt(NxK)^T
// EPI: 0 none | 1 +res | 2 +bias,GELU | 3 +bias,+res
// OMODE: 0 f32 normal | 1 bf16 normal | 2 bf16 transposed-per-head (V^T out)
// ---------------------------------------------------------------------------
template <int EPI, int OMODE>
__global__ __launch_bounds__(256) void mfma_gemm(const bf16* __restrict__ A,
                                                 const bf16* __restrict__ Bt,
                                                 void* __restrict__ Cout,
                                                 int M, int N, int K,
                                                 const float* __restrict__ bias,
                                                 const float* __restrict__ res)
{
    __shared__ bf16 As[128 * 32];
    __shared__ bf16 Bs[128 * 32];
    const int t = threadIdx.x;
    const int w = t >> 6, lane = t & 63;
    const int wr = w >> 1, wc = w & 1;
    const int m0 = blockIdx.y * 128, n0 = blockIdx.x * 128;
    const int lr = lane & 15, lg = lane >> 4;

    f32x4 acc[4][4];
#pragma unroll
    for (int m = 0; m < 4; m++)
#pragma unroll
        for (int n = 0; n < 4; n++) acc[m][n] = {0.f, 0.f, 0.f, 0.f};

    const int q0c = w * 2, q1c = w * 2 + 1;
    const int row0 = q0c * 16 + (lane >> 2);
    const int row1 = q1c * 16 + (lane >> 2);
    const int kk = (lane & 3) * 8;

    for (int k0 = 0; k0 < K; k0 += 32) {
        async_copy16(A  + (size_t)(m0 + row0) * K + k0 + kk, &As[q0c * 512]);
        async_copy16(A  + (size_t)(m0 + row1) * K + k0 + kk, &As[q1c * 512]);
        async_copy16(Bt + (size_t)(n0 + row0) * K + k0 + kk, &Bs[q0c * 512]);
        async_copy16(Bt + (size_t)(n0 + row1) * K + k0 + kk, &Bs[q1c * 512]);
        __syncthreads();

        bf16x8 af[4], bfr[4];
#pragma unroll
        for (int m = 0; m < 4; m++)
            af[m] = *(const bf16x8*)&As[(wr * 64 + m * 16 + lr) * 32 + lg * 8];
#pragma unroll
        for (int n = 0; n < 4; n++)
            bfr[n] = *(const bf16x8*)&Bs[(wc * 64 + n * 16 + lr) * 32 + lg * 8];
#pragma unroll
        for (int m = 0; m < 4; m++)
#pragma unroll
            for (int n = 0; n < 4; n++)
                acc[m][n] = __builtin_amdgcn_mfma_f32_16x16x32_bf16(
                    af[m], bfr[n], acc[m][n], 0, 0, 0);
        __syncthreads();
    }

#pragma unroll
    for (int m = 0; m < 4; m++)
#pragma unroll
        for (int n = 0; n < 4; n++) {
            const int col = n0 + wc * 64 + n * 16 + lr;
            const float bv = (EPI >= 2) ? bias[col] : 0.f;
            if (OMODE == 2) {
                // V^T store: Vt[(b*H + head)*DH + dh][token]
                const int head = col >> 6, dh = col & 63;
                const int row0_ = m0 + wr * 64 + m * 16 + lg * 4;
                const int bb = row0_ >> 11, nn = row0_ & 2047;
                bf16x4 st;
#pragma unroll
                for (int r2 = 0; r2 < 4; r2++) st[r2] = (bf16)acc[m][n][r2];
                *(bf16x4*)((bf16*)Cout +
                           (size_t)((bb * H_ + head) * DH_ + dh) * N_ + nn) = st;
            } else {
#pragma unroll
                for (int r2 = 0; r2 < 4; r2++) {
                    const int row = m0 + wr * 64 + m * 16 + lg * 4 + r2;
                    float v = acc[m][n][r2] + bv;
                    if (EPI == 1 || EPI == 3) v += res[(size_t)row * N + col];
                    if (EPI == 2) v = 0.5f * v * (1.0f + erff(v * 0.70710678118654752f));
                    if (OMODE == 1) ((bf16*)Cout)[(size_t)row * N + col] = (bf16)v;
                    else            ((float*)Cout)[(size_t)row * N + col] = v;
                }
            }
        }
}

// ---------------------------------------------------------------------------
// bf16 MFMA flash attention. NO 1/sqrt(d) scaling (per reference).
// grid (N/128, H, B), 256 threads = 4 waves; wave owns 32 q-rows.
// Q,K: [b][n][h*dh] bf16.  Vt: [(b*H+h)*DH + dh][n] bf16.  O: [b][n][h*dh] bf16.
// K/V tiles staged via global_load_lds with pre-swizzled source chunks
// (slot c at row r holds logical chunk c^(r&7)) -> conflict-free ds_read_b128.
// P goes through per-wave LDS (row stride 72 bf16 = 144B, 16B-aligned).
// ---------------------------------------------------------------------------
__global__ __launch_bounds__(256) void mfma_attn(const bf16* __restrict__ Q,
                                                 const bf16* __restrict__ K,
                                                 const bf16* __restrict__ Vt,
                                                 bf16* __restrict__ O)
{
    const int qt = blockIdx.x, h = blockIdx.y, b = blockIdx.z;
    const int t = threadIdx.x, w = t >> 6, lane = t & 63;
    const int lr = lane & 15, lg = lane >> 4;

    __shared__ bf16 Ks[64 * 64];      // [kv][dh] swizzled
    __shared__ bf16 Vs[64 * 64];      // [dh][kv] swizzled
    __shared__ bf16 Ps[4][32 * 72];   // per-wave P

    // Q fragments (A layout): rows w*32 + mi*16 + lr, dh = ki*32 + lg*8
    const int q0 = qt * 128 + w * 32;
    bf16x8 a_q[2][2];
#pragma unroll
    for (int mi = 0; mi < 2; mi++)
#pragma unroll
        for (int ki = 0; ki < 2; ki++)
            a_q[mi][ki] = *(const bf16x8*)&Q[(size_t)(b * N_ + q0 + mi * 16 + lr) * (H_ * DH_)
                                            + h * DH_ + ki * 32 + lg * 8];

    f32x4 acc_o[2][4];
#pragma unroll
    for (int mi = 0; mi < 2; mi++)
#pragma unroll
        for (int nd = 0; nd < 4; nd++) acc_o[mi][nd] = {0.f, 0.f, 0.f, 0.f};
    float m_run[2][4], l_run[2][4];
#pragma unroll
    for (int mi = 0; mi < 2; mi++)
#pragma unroll
        for (int r2 = 0; r2 < 4; r2++) { m_run[mi][r2] = -3.0e38f; l_run[mi][r2] = 0.f; }

    // staging geometry: lane covers (row = lane>>3, slot = lane&7);
    // source chunk = slot ^ (row&7)
    const int srow = lane >> 3;
    const int schunk = (lane & 7) ^ srow;

    for (int kv0 = 0; kv0 < N_; kv0 += 64) {
#pragma unroll
        for (int i = 0; i < 2; i++) {
            const int r = w * 16 + i * 8 + srow;
            async_copy16(&K[(size_t)(b * N_ + kv0 + r) * (H_ * DH_) + h * DH_ + schunk * 8],
                         &Ks[(w * 16 + i * 8) * 64]);
            async_copy16(&Vt[(size_t)((b * H_ + h) * DH_ + r) * N_ + kv0 + schunk * 8],
                         &Vs[(w * 16 + i * 8) * 64]);
        }
        __syncthreads();

        // ---- S = Q K^T ----
        f32x4 s[2][4];
#pragma unroll
        for (int mi = 0; mi < 2; mi++)
#pragma unroll
            for (int ni = 0; ni < 4; ni++) s[mi][ni] = {0.f, 0.f, 0.f, 0.f};
#pragma unroll
        for (int ki = 0; ki < 2; ki++) {
            bf16x8 bk[4];
#pragma unroll
            for (int ni = 0; ni < 4; ni++) {
                const int r = ni * 16 + lr;
                const int slot = (lg + ki * 4) ^ (r & 7);
                bk[ni] = *(const bf16x8*)&Ks[r * 64 + slot * 8];
            }
#pragma unroll
            for (int mi = 0; mi < 2; mi++)
#pragma unroll
                for (int ni = 0; ni < 4; ni++)
                    s[mi][ni] = __builtin_amdgcn_mfma_f32_16x16x32_bf16(
                        a_q[mi][ki], bk[ni], s[mi][ni], 0, 0, 0);
        }

        // ---- online softmax (all 64 lanes; rows owned per (lg,reg)) ----
#pragma unroll
        for (int mi = 0; mi < 2; mi++) {
            float resc[4], rsum[4];
#pragma unroll
            for (int r2 = 0; r2 < 4; r2++) {
                float v0 = fmaxf(fmaxf(s[mi][0][r2], s[mi][1][r2]),
                                 fmaxf(s[mi][2][r2], s[mi][3][r2]));
#pragma unroll
                for (int off = 1; off <= 8; off <<= 1)
                    v0 = fmaxf(v0, __shfl_xor(v0, off));
                const float mn = fmaxf(m_run[mi][r2], v0);
                resc[r2] = __expf(m_run[mi][r2] - mn);
                m_run[mi][r2] = mn;
                rsum[r2] = 0.f;
            }
#pragma unroll
            for (int ni = 0; ni < 4; ni++)
#pragma unroll
                for (int r2 = 0; r2 < 4; r2++) {
                    const float p = __expf(s[mi][ni][r2] - m_run[mi][r2]);
                    rsum[r2] += p;
                    Ps[w][(mi * 16 + lg * 4 + r2) * 72 + ni * 16 + lr] = (bf16)p;
                }
#pragma unroll
            for (int r2 = 0; r2 < 4; r2++) {
                float sr = rsum[r2];
#pragma unroll
                for (int off = 1; off <= 8; off <<= 1) sr += __shfl_xor(sr, off);
                l_run[mi][r2] = l_run[mi][r2] * resc[r2] + sr;
#pragma unroll
                for (int nd = 0; nd < 4; nd++) acc_o[mi][nd][r2] *= resc[r2];
            }
        }

        // ---- O += P V ----
        bf16x8 a_p[2][2];
#pragma unroll
        for (int mi = 0; mi < 2; mi++)
#pragma unroll
            for (int k2 = 0; k2 < 2; k2++)
                a_p[mi][k2] = *(const bf16x8*)&Ps[w][(mi * 16 + lr) * 72 + k2 * 32 + lg * 8];
#pragma unroll
        for (int k2 = 0; k2 < 2; k2++) {
            bf16x8 bv[4];
#pragma unroll
            for (int nd = 0; nd < 4; nd++) {
                const int r = nd * 16 + lr;
                const int slot = (lg + k2 * 4) ^ (r & 7);
                bv[nd] = *(const bf16x8*)&Vs[r * 64 + slot * 8];
            }
#pragma unroll
            for (int mi = 0; mi < 2; mi++)
#pragma unroll
                for (int nd = 0; nd < 4; nd++)
                    acc_o[mi][nd] = __builtin_amdgcn_mfma_f32_16x16x32_bf16(
                        a_p[mi][k2], bv[nd], acc_o[mi][nd], 0, 0, 0);
        }
        __syncthreads();
    }

    // ---- epilogue: O / l ----
#pragma unroll
    for (int mi = 0; mi < 2; mi++) {
        float inv[4];
#pragma unroll
        for (int r2 = 0; r2 < 4; r2++) inv[r2] = 1.f / l_run[mi][r2];
#pragma unroll
        for (int nd = 0; nd < 4; nd++)
#pragma unroll
            for (int r2 = 0; r2 < 4; r2++) {
                const int qrow = q0 + mi * 16 + lg * 4 + r2;
                const int d = nd * 16 + lr;
                O[(size_t)(b * N_ + qrow) * (H_ * DH_) + h * DH_ + d] =
                    (bf16)(acc_o[mi][nd][r2] * inv[r2]);
            }
    }
}

// ---------------------------------------------------------------------------
extern "C" void kernel_launch(void* const* d_in, const int* in_sizes, int n_in,
                              void* d_out, int out_size, void* d_ws, size_t ws_size,
                              hipStream_t stream)
{
    const float* x     = (const float*)d_in[0];
    const float* wq    = (const float*)d_in[1];
    const float* wk    = (const float*)d_in[2];
    const float* wv    = (const float*)d_in[3];
    const float* wo    = (const float*)d_in[4];
    const float* w1    = (const float*)d_in[5];
    const float* b1    = (const float*)d_in[6];
    const float* w2    = (const float*)d_in[7];
    const float* b2    = (const float*)d_in[8];
    const float* ln1_g = (const float*)d_in[9];
    const float* ln1_b = (const float*)d_in[10];
    const float* ln2_g = (const float*)d_in[11];
    const float* ln2_b = (const float*)d_in[12];

    const size_t MD = (size_t)M_ * D_;
    char* wsb = (char*)d_ws;
    auto alloc = [&](size_t bytes) { char* p = wsb; wsb += (bytes + 255) & ~(size_t)255; return p; };
    bf16*  hb  = (bf16*)alloc(MD * 2);                 // LN1 out
    bf16*  qb  = (bf16*)alloc(MD * 2);                 // Q bf16
    bf16*  kb  = (bf16*)alloc(MD * 2);                 // K bf16
    bf16*  vtb = (bf16*)alloc(MD * 2);                 // V^T bf16 [bh*dh][n]
    bf16*  ab  = (bf16*)alloc(MD * 2);                 // attn out
    float* x1  = (float*)alloc(MD * 4);                // residual after attn
    bf16*  h2b = (bf16*)alloc(MD * 2);                 // LN2 out
    bf16*  ffb = (bf16*)alloc((size_t)M_ * FF_ * 2);   // GELU out
    bf16*  wqT = (bf16*)alloc((size_t)D_ * D_ * 2);
    bf16*  wkT = (bf16*)alloc((size_t)D_ * D_ * 2);
    bf16*  wvT = (bf16*)alloc((size_t)D_ * D_ * 2);
    bf16*  woT = (bf16*)alloc((size_t)D_ * D_ * 2);
    bf16*  w1T = (bf16*)alloc((size_t)D_ * FF_ * 2);
    bf16*  w2T = (bf16*)alloc((size_t)FF_ * D_ * 2);

    dim3 tb(32, 8);
    transpose_bf16<<<dim3(D_ / 32, D_ / 32), tb, 0, stream>>>(wq, wqT, D_, D_);
    transpose_bf16<<<dim3(D_ / 32, D_ / 32), tb, 0, stream>>>(wk, wkT, D_, D_);
    transpose_bf16<<<dim3(D_ / 32, D_ / 32), tb, 0, stream>>>(wv, wvT, D_, D_);
    transpose_bf16<<<dim3(D_ / 32, D_ / 32), tb, 0, stream>>>(wo, woT, D_, D_);
    transpose_bf16<<<dim3(FF_ / 32, D_ / 32), tb, 0, stream>>>(w1, w1T, D_, FF_);
    transpose_bf16<<<dim3(D_ / 32, FF_ / 32), tb, 0, stream>>>(w2, w2T, FF_, D_);

    // 1. LN1
    ln_kernel<<<M_, 256, 0, stream>>>(x, ln1_g, ln1_b, hb);

    // 2. QKV projections (bf16 out; V transposed per head)
    dim3 gP(D_ / 128, M_ / 128);
    mfma_gemm<0, 1><<<gP, 256, 0, stream>>>(hb, wqT, qb, M_, D_, D_, nullptr, nullptr);
    mfma_gemm<0, 1><<<gP, 256, 0, stream>>>(hb, wkT, kb, M_, D_, D_, nullptr, nullptr);
    mfma_gemm<0, 2><<<gP, 256, 0, stream>>>(hb, wvT, vtb, M_, D_, D_, nullptr, nullptr);

    // 3. MFMA flash attention
    mfma_attn<<<dim3(N_ / 128, H_, B_), 256, 0, stream>>>(qb, kb, vtb, ab);

    // 4. x1 = attn @ wo + x
    mfma_gemm<1, 0><<<gP, 256, 0, stream>>>(ab, woT, x1, M_, D_, D_, nullptr, x);

    // 5. LN2
    ln_kernel<<<M_, 256, 0, stream>>>(x1, ln2_g, ln2_b, h2b);

    // 6. ff = GELU(h2 @ w1 + b1)
    mfma_gemm<2, 1><<<dim3(FF_ / 128, M_ / 128), 256, 0, stream>>>(
        h2b, w1T, ffb, M_, FF_, D_, b1, nullptr);

    // 7. out = ff @ w2 + b2 + x1
    mfma_gemm<3, 0><<<dim3(D_ / 128, M_ / 128), 256, 0, stream>>>(
        ffb, w2T, (float*)d_out, M_, D_, FF_, b2, x1);
}

// Round 7
// 476.347 us; speedup vs baseline: 5.8745x; 1.1280x over previous
//
#include <hip/hip_runtime.h>
#include <math.h>
#include <stdint.h>

#define B_  2
#define N_  2048
#define D_  1024
#define H_  16
#define DH_ 64
#define FF_ 4096
#define M_  (B_ * N_)   // 4096 rows total

typedef __bf16 bf16;
typedef float  f32x4  __attribute__((ext_vector_type(4)));
typedef __bf16 bf16x8 __attribute__((ext_vector_type(8)));
typedef __bf16 bf16x4 __attribute__((ext_vector_type(4)));

// async global->LDS, 16B per lane; LDS dest = wave-uniform base + lane*16
__device__ __forceinline__ void async_copy16(const void* g, void* l) {
    __builtin_amdgcn_global_load_lds((__attribute__((address_space(1))) unsigned int*)g,
                                     (__attribute__((address_space(3))) unsigned int*)l,
                                     16, 0, 0);
}

// ---------------------------------------------------------------------------
// LayerNorm: one block per row, 256 threads, D=1024. fp32 in, bf16 out.
// ---------------------------------------------------------------------------
__global__ __launch_bounds__(256) void ln_kernel(const float* __restrict__ x,
                                                 const float* __restrict__ g,
                                                 const float* __restrict__ bta,
                                                 bf16* __restrict__ y)
{
    const int row = blockIdx.x;
    const int t = threadIdx.x;
    const float4 v = ((const float4*)(x + (size_t)row * D_))[t];
    float s  = v.x + v.y + v.z + v.w;
    float s2 = v.x * v.x + v.y * v.y + v.z * v.z + v.w * v.w;
#pragma unroll
    for (int o = 32; o > 0; o >>= 1) {
        s  += __shfl_down(s, o);
        s2 += __shfl_down(s2, o);
    }
    __shared__ float red[8];
    const int wid = t >> 6;
    if ((t & 63) == 0) { red[wid] = s; red[4 + wid] = s2; }
    __syncthreads();
    if (t == 0) {
        red[0] = red[0] + red[1] + red[2] + red[3];
        red[4] = red[4] + red[5] + red[6] + red[7];
    }
    __syncthreads();
    const float mean = red[0] * (1.0f / D_);
    const float var  = red[4] * (1.0f / D_) - mean * mean;
    const float rstd = rsqrtf(var + 1e-5f);
    const float4 gg = ((const float4*)g)[t];
    const float4 bb = ((const float4*)bta)[t];
    bf16x4 o;
    o[0] = (bf16)((v.x - mean) * rstd * gg.x + bb.x);
    o[1] = (bf16)((v.y - mean) * rstd * gg.y + bb.y);
    o[2] = (bf16)((v.z - mean) * rstd * gg.z + bb.z);
    o[3] = (bf16)((v.w - mean) * rstd * gg.w + bb.w);
    ((bf16x4*)(y + (size_t)row * D_))[t] = o;
}

// ---------------------------------------------------------------------------
// fp32 [R][C] -> bf16 [C][R] transpose (weights, once per launch).
// ---------------------------------------------------------------------------
__global__ __launch_bounds__(256) void transpose_bf16(const float* __restrict__ in,
                                                      bf16* __restrict__ out,
                                                      int R, int C)
{
    __shared__ float tile[32][33];
    const int c0 = blockIdx.x * 32, r0 = blockIdx.y * 32;
    const int tx = threadIdx.x, ty = threadIdx.y;  // (32,8)
#pragma unroll
    for (int i = 0; i < 4; i++)
        tile[ty + i * 8][tx] = in[(size_t)(r0 + ty + i * 8) * C + c0 + tx];
    __syncthreads();
#pragma unroll
    for (int i = 0; i < 4; i++)
        out[(size_t)(c0 + ty + i * 8) * R + r0 + tx] = (bf16)tile[tx][ty + i * 8];
}

// 3 D_xD_ sources -> one [3*D_][D_] bf16 transposed buffer (z = which source)
__global__ __launch_bounds__(256) void transpose3_bf16(const float* __restrict__ a,
                                                       const float* __restrict__ b,
                                                       const float* __restrict__ c,
                                                       bf16* __restrict__ out)
{
    __shared__ float tile[32][33];
    const float* in = (blockIdx.z == 0) ? a : (blockIdx.z == 1) ? b : c;
    bf16* o = out + (size_t)blockIdx.z * D_ * D_;
    const int c0 = blockIdx.x * 32, r0 = blockIdx.y * 32;
    const int tx = threadIdx.x, ty = threadIdx.y;  // (32,8)
#pragma unroll
    for (int i = 0; i < 4; i++)
        tile[ty + i * 8][tx] = in[(size_t)(r0 + ty + i * 8) * D_ + c0 + tx];
    __syncthreads();
#pragma unroll
    for (int i = 0; i < 4; i++)
        o[(size_t)(c0 + ty + i * 8) * D_ + r0 + tx] = (bf16)tile[tx][ty + i * 8];
}

// ---------------------------------------------------------------------------
// bf16 MFMA GEMM (m97 structure): C(MxN) = A(MxK) @ Bt(NxK)^T
// EPI: 0 none | 1 +res | 2 +bias,GELU | 3 +bias,+res
// OMODE: 0 f32 | 1 bf16 | 3 fused-QKV routing (Cout = qb; qb,kb,vtb contiguous;
//        col slice 0 -> Q bf16 [row][c], 1 -> K bf16, 2 -> V^T per head)
// ---------------------------------------------------------------------------
template <int EPI, int OMODE>
__global__ __launch_bounds__(256) void mfma_gemm(const bf16* __restrict__ A,
                                                 const bf16* __restrict__ Bt,
                                                 void* __restrict__ Cout,
                                                 int M, int N, int K,
                                                 const float* __restrict__ bias,
                                                 const float* __restrict__ res)
{
    __shared__ bf16 As[128 * 32];
    __shared__ bf16 Bs[128 * 32];
    const int t = threadIdx.x;
    const int w = t >> 6, lane = t & 63;
    const int wr = w >> 1, wc = w & 1;
    const int m0 = blockIdx.y * 128, n0 = blockIdx.x * 128;
    const int lr = lane & 15, lg = lane >> 4;
    const size_t MDc = (size_t)M_ * D_;

    f32x4 acc[4][4];
#pragma unroll
    for (int m = 0; m < 4; m++)
#pragma unroll
        for (int n = 0; n < 4; n++) acc[m][n] = {0.f, 0.f, 0.f, 0.f};

    const int q0c = w * 2, q1c = w * 2 + 1;
    const int row0 = q0c * 16 + (lane >> 2);
    const int row1 = q1c * 16 + (lane >> 2);
    const int kk = (lane & 3) * 8;

    for (int k0 = 0; k0 < K; k0 += 32) {
        async_copy16(A  + (size_t)(m0 + row0) * K + k0 + kk, &As[q0c * 512]);
        async_copy16(A  + (size_t)(m0 + row1) * K + k0 + kk, &As[q1c * 512]);
        async_copy16(Bt + (size_t)(n0 + row0) * K + k0 + kk, &Bs[q0c * 512]);
        async_copy16(Bt + (size_t)(n0 + row1) * K + k0 + kk, &Bs[q1c * 512]);
        __syncthreads();

        bf16x8 af[4], bfr[4];
#pragma unroll
        for (int m = 0; m < 4; m++)
            af[m] = *(const bf16x8*)&As[(wr * 64 + m * 16 + lr) * 32 + lg * 8];
#pragma unroll
        for (int n = 0; n < 4; n++)
            bfr[n] = *(const bf16x8*)&Bs[(wc * 64 + n * 16 + lr) * 32 + lg * 8];
#pragma unroll
        for (int m = 0; m < 4; m++)
#pragma unroll
            for (int n = 0; n < 4; n++)
                acc[m][n] = __builtin_amdgcn_mfma_f32_16x16x32_bf16(
                    af[m], bfr[n], acc[m][n], 0, 0, 0);
        __syncthreads();
    }

#pragma unroll
    for (int m = 0; m < 4; m++)
#pragma unroll
        for (int n = 0; n < 4; n++) {
            const int col = n0 + wc * 64 + n * 16 + lr;
            const float bv = (EPI >= 2) ? bias[col] : 0.f;
            if (OMODE == 3) {
                const int slice = col >> 10;       // 0=Q 1=K 2=V (uniform per frag)
                const int c = col & 1023;
                if (slice == 2) {
                    const int head = c >> 6, dh = c & 63;
                    const int row0_ = m0 + wr * 64 + m * 16 + lg * 4;
                    const int bb = row0_ >> 11, nn = row0_ & 2047;
                    bf16x4 st;
#pragma unroll
                    for (int r2 = 0; r2 < 4; r2++) st[r2] = (bf16)acc[m][n][r2];
                    *(bf16x4*)((bf16*)Cout + 2 * MDc +
                               (size_t)((bb * H_ + head) * DH_ + dh) * N_ + nn) = st;
                } else {
                    bf16* dst = (bf16*)Cout + (size_t)slice * MDc;
#pragma unroll
                    for (int r2 = 0; r2 < 4; r2++) {
                        const int row = m0 + wr * 64 + m * 16 + lg * 4 + r2;
                        dst[(size_t)row * D_ + c] = (bf16)acc[m][n][r2];
                    }
                }
            } else {
#pragma unroll
                for (int r2 = 0; r2 < 4; r2++) {
                    const int row = m0 + wr * 64 + m * 16 + lg * 4 + r2;
                    float v = acc[m][n][r2] + bv;
                    if (EPI == 1 || EPI == 3) v += res[(size_t)row * N + col];
                    if (EPI == 2) v = 0.5f * v * (1.0f + erff(v * 0.70710678118654752f));
                    if (OMODE == 1) ((bf16*)Cout)[(size_t)row * N + col] = (bf16)v;
                    else            ((float*)Cout)[(size_t)row * N + col] = v;
                }
            }
        }
}

// ---------------------------------------------------------------------------
// bf16 MFMA flash attention, double-buffered K/V (T3-minimum schedule:
// stage t+1 early -> compute t -> ONE barrier/iter; the vmcnt(0) drain at the
// barrier now lands after ~full compute phase, hiding HBM latency at 2 blk/CU).
// grid (N/128, H, B), 4 waves; wave owns 32 q-rows. NO 1/sqrt(d) scaling.
// Ks/Vs staged via global_load_lds, source pre-swizzled chunk c^(r&7);
// reads use the same involution -> conflict-free ds_read_b128.
// ---------------------------------------------------------------------------
__global__ __launch_bounds__(256) void mfma_attn(const bf16* __restrict__ Q,
                                                 const bf16* __restrict__ K,
                                                 const bf16* __restrict__ Vt,
                                                 bf16* __restrict__ O)
{
    const int qt = blockIdx.x, h = blockIdx.y, b = blockIdx.z;
    const int t = threadIdx.x, w = t >> 6, lane = t & 63;
    const int lr = lane & 15, lg = lane >> 4;

    __shared__ bf16 Ks[2][64 * 64];   // [buf][kv][dh] swizzled
    __shared__ bf16 Vs[2][64 * 64];   // [buf][dh][kv] swizzled
    __shared__ bf16 Ps[4][32 * 72];   // per-wave P

    const int q0 = qt * 128 + w * 32;
    bf16x8 a_q[2][2];
#pragma unroll
    for (int mi = 0; mi < 2; mi++)
#pragma unroll
        for (int ki = 0; ki < 2; ki++)
            a_q[mi][ki] = *(const bf16x8*)&Q[(size_t)(b * N_ + q0 + mi * 16 + lr) * (H_ * DH_)
                                            + h * DH_ + ki * 32 + lg * 8];

    f32x4 acc_o[2][4];
#pragma unroll
    for (int mi = 0; mi < 2; mi++)
#pragma unroll
        for (int nd = 0; nd < 4; nd++) acc_o[mi][nd] = {0.f, 0.f, 0.f, 0.f};
    float m_run[2][4], l_run[2][4];
#pragma unroll
    for (int mi = 0; mi < 2; mi++)
#pragma unroll
        for (int r2 = 0; r2 < 4; r2++) { m_run[mi][r2] = -3.0e38f; l_run[mi][r2] = 0.f; }

    // staging geometry: lane -> (row = lane>>3, slot = lane&7), chunk = slot^row
    const int srow = lane >> 3;
    const int schunk = (lane & 7) ^ srow;
    const size_t kbase = (size_t)b * N_ * (H_ * DH_) + (size_t)h * DH_ + schunk * 8;
    const size_t vbase = ((size_t)(b * H_ + h) * DH_) * N_;

    auto stage = [&](int kv0, int buf) {
#pragma unroll
        for (int i = 0; i < 2; i++) {
            const int r = w * 16 + i * 8 + srow;
            async_copy16(&K[kbase + (size_t)(kv0 + r) * (H_ * DH_)],
                         &Ks[buf][(w * 16 + i * 8) * 64]);
            async_copy16(&Vt[vbase + (size_t)r * N_ + kv0 + schunk * 8],
                         &Vs[buf][(w * 16 + i * 8) * 64]);
        }
    };

    stage(0, 0);                                   // prologue
    const int NT = N_ / 64;
    for (int it = 0; it < NT; ++it) {
        __syncthreads();                           // buf it&1 staged (vmcnt drain)
        if (it + 1 < NT) stage((it + 1) * 64, (it + 1) & 1);  // prefetch next
        const bf16* ks = Ks[it & 1];
        const bf16* vs = Vs[it & 1];

        // ---- S = Q K^T ----
        f32x4 s[2][4];
#pragma unroll
        for (int mi = 0; mi < 2; mi++)
#pragma unroll
            for (int ni = 0; ni < 4; ni++) s[mi][ni] = {0.f, 0.f, 0.f, 0.f};
        __builtin_amdgcn_s_setprio(1);
#pragma unroll
        for (int ki = 0; ki < 2; ki++) {
            bf16x8 bk[4];
#pragma unroll
            for (int ni = 0; ni < 4; ni++) {
                const int r = ni * 16 + lr;
                const int slot = (lg + ki * 4) ^ (r & 7);
                bk[ni] = *(const bf16x8*)&ks[r * 64 + slot * 8];
            }
#pragma unroll
            for (int mi = 0; mi < 2; mi++)
#pragma unroll
                for (int ni = 0; ni < 4; ni++)
                    s[mi][ni] = __builtin_amdgcn_mfma_f32_16x16x32_bf16(
                        a_q[mi][ki], bk[ni], s[mi][ni], 0, 0, 0);
        }
        __builtin_amdgcn_s_setprio(0);

        // ---- online softmax (all 64 lanes) ----
#pragma unroll
        for (int mi = 0; mi < 2; mi++) {
            float resc[4], rsum[4];
#pragma unroll
            for (int r2 = 0; r2 < 4; r2++) {
                float v0 = fmaxf(fmaxf(s[mi][0][r2], s[mi][1][r2]),
                                 fmaxf(s[mi][2][r2], s[mi][3][r2]));
#pragma unroll
                for (int off = 1; off <= 8; off <<= 1)
                    v0 = fmaxf(v0, __shfl_xor(v0, off));
                const float mn = fmaxf(m_run[mi][r2], v0);
                resc[r2] = __expf(m_run[mi][r2] - mn);
                m_run[mi][r2] = mn;
                rsum[r2] = 0.f;
            }
#pragma unroll
            for (int ni = 0; ni < 4; ni++)
#pragma unroll
                for (int r2 = 0; r2 < 4; r2++) {
                    const float p = __expf(s[mi][ni][r2] - m_run[mi][r2]);
                    rsum[r2] += p;
                    Ps[w][(mi * 16 + lg * 4 + r2) * 72 + ni * 16 + lr] = (bf16)p;
                }
#pragma unroll
            for (int r2 = 0; r2 < 4; r2++) {
                float sr = rsum[r2];
#pragma unroll
                for (int off = 1; off <= 8; off <<= 1) sr += __shfl_xor(sr, off);
                l_run[mi][r2] = l_run[mi][r2] * resc[r2] + sr;
#pragma unroll
                for (int nd = 0; nd < 4; nd++) acc_o[mi][nd][r2] *= resc[r2];
            }
        }

        // ---- O += P V ----
        bf16x8 a_p[2][2];
#pragma unroll
        for (int mi = 0; mi < 2; mi++)
#pragma unroll
            for (int k2 = 0; k2 < 2; k2++)
                a_p[mi][k2] = *(const bf16x8*)&Ps[w][(mi * 16 + lr) * 72 + k2 * 32 + lg * 8];
        __builtin_amdgcn_s_setprio(1);
#pragma unroll
        for (int k2 = 0; k2 < 2; k2++) {
            bf16x8 bv[4];
#pragma unroll
            for (int nd = 0; nd < 4; nd++) {
                const int r = nd * 16 + lr;
                const int slot = (lg + k2 * 4) ^ (r & 7);
                bv[nd] = *(const bf16x8*)&vs[r * 64 + slot * 8];
            }
#pragma unroll
            for (int mi = 0; mi < 2; mi++)
#pragma unroll
                for (int nd = 0; nd < 4; nd++)
                    acc_o[mi][nd] = __builtin_amdgcn_mfma_f32_16x16x32_bf16(
                        a_p[mi][k2], bv[nd], acc_o[mi][nd], 0, 0, 0);
        }
        __builtin_amdgcn_s_setprio(0);
    }

    // ---- epilogue: O / l ----
#pragma unroll
    for (int mi = 0; mi < 2; mi++) {
        float inv[4];
#pragma unroll
        for (int r2 = 0; r2 < 4; r2++) inv[r2] = 1.f / l_run[mi][r2];
#pragma unroll
        for (int nd = 0; nd < 4; nd++)
#pragma unroll
            for (int r2 = 0; r2 < 4; r2++) {
                const int qrow = q0 + mi * 16 + lg * 4 + r2;
                const int d = nd * 16 + lr;
                O[(size_t)(b * N_ + qrow) * (H_ * DH_) + h * DH_ + d] =
                    (bf16)(acc_o[mi][nd][r2] * inv[r2]);
            }
    }
}

// ---------------------------------------------------------------------------
extern "C" void kernel_launch(void* const* d_in, const int* in_sizes, int n_in,
                              void* d_out, int out_size, void* d_ws, size_t ws_size,
                              hipStream_t stream)
{
    const float* x     = (const float*)d_in[0];
    const float* wq    = (const float*)d_in[1];
    const float* wk    = (const float*)d_in[2];
    const float* wv    = (const float*)d_in[3];
    const float* wo    = (const float*)d_in[4];
    const float* w1    = (const float*)d_in[5];
    const float* b1    = (const float*)d_in[6];
    const float* w2    = (const float*)d_in[7];
    const float* b2    = (const float*)d_in[8];
    const float* ln1_g = (const float*)d_in[9];
    const float* ln1_b = (const float*)d_in[10];
    const float* ln2_g = (const float*)d_in[11];
    const float* ln2_b = (const float*)d_in[12];

    const size_t MD = (size_t)M_ * D_;
    char* wsb = (char*)d_ws;
    auto alloc = [&](size_t bytes) { char* p = wsb; wsb += (bytes + 255) & ~(size_t)255; return p; };
    bf16*  hb    = (bf16*)alloc(MD * 2);               // LN1 out
    bf16*  qb    = (bf16*)alloc(MD * 2 * 3);           // Q | K | V^T contiguous
    bf16*  kb    = qb + MD;
    bf16*  vtb   = qb + 2 * MD;
    bf16*  ab    = (bf16*)alloc(MD * 2);               // attn out
    float* x1    = (float*)alloc(MD * 4);              // residual after attn
    bf16*  h2b   = (bf16*)alloc(MD * 2);               // LN2 out
    bf16*  ffb   = (bf16*)alloc((size_t)M_ * FF_ * 2); // GELU out
    bf16*  wqkvT = (bf16*)alloc((size_t)3 * D_ * D_ * 2);
    bf16*  woT   = (bf16*)alloc((size_t)D_ * D_ * 2);
    bf16*  w1T   = (bf16*)alloc((size_t)D_ * FF_ * 2);
    bf16*  w2T   = (bf16*)alloc((size_t)FF_ * D_ * 2);

    dim3 tb(32, 8);
    transpose3_bf16<<<dim3(D_ / 32, D_ / 32, 3), tb, 0, stream>>>(wq, wk, wv, wqkvT);
    transpose_bf16<<<dim3(D_ / 32, D_ / 32), tb, 0, stream>>>(wo, woT, D_, D_);
    transpose_bf16<<<dim3(FF_ / 32, D_ / 32), tb, 0, stream>>>(w1, w1T, D_, FF_);
    transpose_bf16<<<dim3(D_ / 32, FF_ / 32), tb, 0, stream>>>(w2, w2T, FF_, D_);

    // 1. LN1
    ln_kernel<<<M_, 256, 0, stream>>>(x, ln1_g, ln1_b, hb);

    // 2. fused QKV projection (N=3072; epilogue routes Q/K/V^T)
    mfma_gemm<0, 3><<<dim3(3 * D_ / 128, M_ / 128), 256, 0, stream>>>(
        hb, wqkvT, qb, M_, 3 * D_, D_, nullptr, nullptr);

    // 3. MFMA flash attention (double-buffered)
    mfma_attn<<<dim3(N_ / 128, H_, B_), 256, 0, stream>>>(qb, kb, vtb, ab);

    // 4. x1 = attn @ wo + x
    dim3 gP(D_ / 128, M_ / 128);
    mfma_gemm<1, 0><<<gP, 256, 0, stream>>>(ab, woT, x1, M_, D_, D_, nullptr, x);

    // 5. LN2
    ln_kernel<<<M_, 256, 0, stream>>>(x1, ln2_g, ln2_b, h2b);

    // 6. ff = GELU(h2 @ w1 + b1)
    mfma_gemm<2, 1><<<dim3(FF_ / 128, M_ / 128), 256, 0, stream>>>(
        h2b, w1T, ffb, M_, FF_, D_, b1, nullptr);

    // 7. out = ff @ w2 + b2 + x1
    mfma_gemm<3, 0><<<dim3(D_ / 128, M_ / 128), 256, 0, stream>>>(
        ffb, w2T, (float*)d_out, M_, D_, FF_, b2, x1);
}

// Round 8
// 420.703 us; speedup vs baseline: 6.6515x; 1.1323x over previous
//
#include <hip/hip_runtime.h>
#include <math.h>
#include <stdint.h>

#define B_  2
#define N_  2048
#define D_  1024
#define H_  16
#define DH_ 64
#define FF_ 4096
#define M_  (B_ * N_)   // 4096 rows total

typedef __bf16 bf16;
typedef float  f32x4  __attribute__((ext_vector_type(4)));
typedef __bf16 bf16x8 __attribute__((ext_vector_type(8)));
typedef __bf16 bf16x4 __attribute__((ext_vector_type(4)));
typedef __bf16 bf16x2 __attribute__((ext_vector_type(2)));

// async global->LDS, 16B per lane; LDS dest = wave-uniform base + lane*16
__device__ __forceinline__ void async_copy16(const void* g, void* l) {
    __builtin_amdgcn_global_load_lds((__attribute__((address_space(1))) unsigned int*)g,
                                     (__attribute__((address_space(3))) unsigned int*)l,
                                     16, 0, 0);
}

// ---------------------------------------------------------------------------
// LayerNorm: one block per row, 256 threads, D=1024. fp32 in, bf16 out.
// ---------------------------------------------------------------------------
__global__ __launch_bounds__(256) void ln_kernel(const float* __restrict__ x,
                                                 const float* __restrict__ g,
                                                 const float* __restrict__ bta,
                                                 bf16* __restrict__ y)
{
    const int row = blockIdx.x;
    const int t = threadIdx.x;
    const float4 v = ((const float4*)(x + (size_t)row * D_))[t];
    float s  = v.x + v.y + v.z + v.w;
    float s2 = v.x * v.x + v.y * v.y + v.z * v.z + v.w * v.w;
#pragma unroll
    for (int o = 32; o > 0; o >>= 1) {
        s  += __shfl_down(s, o);
        s2 += __shfl_down(s2, o);
    }
    __shared__ float red[8];
    const int wid = t >> 6;
    if ((t & 63) == 0) { red[wid] = s; red[4 + wid] = s2; }
    __syncthreads();
    if (t == 0) {
        red[0] = red[0] + red[1] + red[2] + red[3];
        red[4] = red[4] + red[5] + red[6] + red[7];
    }
    __syncthreads();
    const float mean = red[0] * (1.0f / D_);
    const float var  = red[4] * (1.0f / D_) - mean * mean;
    const float rstd = rsqrtf(var + 1e-5f);
    const float4 gg = ((const float4*)g)[t];
    const float4 bb = ((const float4*)bta)[t];
    bf16x4 o;
    o[0] = (bf16)((v.x - mean) * rstd * gg.x + bb.x);
    o[1] = (bf16)((v.y - mean) * rstd * gg.y + bb.y);
    o[2] = (bf16)((v.z - mean) * rstd * gg.z + bb.z);
    o[3] = (bf16)((v.w - mean) * rstd * gg.w + bb.w);
    ((bf16x4*)(y + (size_t)row * D_))[t] = o;
}

// ---------------------------------------------------------------------------
// fp32 [R][C] -> bf16 [C][R] transpose (weights, once per launch).
// ---------------------------------------------------------------------------
__global__ __launch_bounds__(256) void transpose_bf16(const float* __restrict__ in,
                                                      bf16* __restrict__ out,
                                                      int R, int C)
{
    __shared__ float tile[32][33];
    const int c0 = blockIdx.x * 32, r0 = blockIdx.y * 32;
    const int tx = threadIdx.x, ty = threadIdx.y;  // (32,8)
#pragma unroll
    for (int i = 0; i < 4; i++)
        tile[ty + i * 8][tx] = in[(size_t)(r0 + ty + i * 8) * C + c0 + tx];
    __syncthreads();
#pragma unroll
    for (int i = 0; i < 4; i++)
        out[(size_t)(c0 + ty + i * 8) * R + r0 + tx] = (bf16)tile[tx][ty + i * 8];
}

// 3 D_xD_ sources -> one [3*D_][D_] bf16 transposed buffer (z = which source)
__global__ __launch_bounds__(256) void transpose3_bf16(const float* __restrict__ a,
                                                       const float* __restrict__ b,
                                                       const float* __restrict__ c,
                                                       bf16* __restrict__ out)
{
    __shared__ float tile[32][33];
    const float* in = (blockIdx.z == 0) ? a : (blockIdx.z == 1) ? b : c;
    bf16* o = out + (size_t)blockIdx.z * D_ * D_;
    const int c0 = blockIdx.x * 32, r0 = blockIdx.y * 32;
    const int tx = threadIdx.x, ty = threadIdx.y;  // (32,8)
#pragma unroll
    for (int i = 0; i < 4; i++)
        tile[ty + i * 8][tx] = in[(size_t)(r0 + ty + i * 8) * D_ + c0 + tx];
    __syncthreads();
#pragma unroll
    for (int i = 0; i < 4; i++)
        o[(size_t)(c0 + ty + i * 8) * D_ + r0 + tx] = (bf16)tile[tx][ty + i * 8];
}

// ---------------------------------------------------------------------------
// bf16 MFMA GEMM (m97 structure): C(MxN) = A(MxK) @ Bt(NxK)^T
// EPI: 0 none | 1 +res | 2 +bias,GELU | 3 +bias,+res
// OMODE: 0 f32 | 1 bf16 | 3 fused-QKV routing (Cout = qb; qb,kb,vtb contiguous;
//        col slice 0 -> Q bf16 [row][c], 1 -> K bf16, 2 -> V^T per head)
// ---------------------------------------------------------------------------
template <int EPI, int OMODE>
__global__ __launch_bounds__(256) void mfma_gemm(const bf16* __restrict__ A,
                                                 const bf16* __restrict__ Bt,
                                                 void* __restrict__ Cout,
                                                 int M, int N, int K,
                                                 const float* __restrict__ bias,
                                                 const float* __restrict__ res)
{
    __shared__ bf16 As[128 * 32];
    __shared__ bf16 Bs[128 * 32];
    const int t = threadIdx.x;
    const int w = t >> 6, lane = t & 63;
    const int wr = w >> 1, wc = w & 1;
    const int m0 = blockIdx.y * 128, n0 = blockIdx.x * 128;
    const int lr = lane & 15, lg = lane >> 4;
    const size_t MDc = (size_t)M_ * D_;

    f32x4 acc[4][4];
#pragma unroll
    for (int m = 0; m < 4; m++)
#pragma unroll
        for (int n = 0; n < 4; n++) acc[m][n] = {0.f, 0.f, 0.f, 0.f};

    const int q0c = w * 2, q1c = w * 2 + 1;
    const int row0 = q0c * 16 + (lane >> 2);
    const int row1 = q1c * 16 + (lane >> 2);
    const int kk = (lane & 3) * 8;

    for (int k0 = 0; k0 < K; k0 += 32) {
        async_copy16(A  + (size_t)(m0 + row0) * K + k0 + kk, &As[q0c * 512]);
        async_copy16(A  + (size_t)(m0 + row1) * K + k0 + kk, &As[q1c * 512]);
        async_copy16(Bt + (size_t)(n0 + row0) * K + k0 + kk, &Bs[q0c * 512]);
        async_copy16(Bt + (size_t)(n0 + row1) * K + k0 + kk, &Bs[q1c * 512]);
        __syncthreads();

        bf16x8 af[4], bfr[4];
#pragma unroll
        for (int m = 0; m < 4; m++)
            af[m] = *(const bf16x8*)&As[(wr * 64 + m * 16 + lr) * 32 + lg * 8];
#pragma unroll
        for (int n = 0; n < 4; n++)
            bfr[n] = *(const bf16x8*)&Bs[(wc * 64 + n * 16 + lr) * 32 + lg * 8];
#pragma unroll
        for (int m = 0; m < 4; m++)
#pragma unroll
            for (int n = 0; n < 4; n++)
                acc[m][n] = __builtin_amdgcn_mfma_f32_16x16x32_bf16(
                    af[m], bfr[n], acc[m][n], 0, 0, 0);
        __syncthreads();
    }

#pragma unroll
    for (int m = 0; m < 4; m++)
#pragma unroll
        for (int n = 0; n < 4; n++) {
            const int col = n0 + wc * 64 + n * 16 + lr;
            const float bv = (EPI >= 2) ? bias[col] : 0.f;
            if (OMODE == 3) {
                const int slice = col >> 10;       // 0=Q 1=K 2=V (uniform per frag)
                const int c = col & 1023;
                if (slice == 2) {
                    const int head = c >> 6, dh = c & 63;
                    const int row0_ = m0 + wr * 64 + m * 16 + lg * 4;
                    const int bb = row0_ >> 11, nn = row0_ & 2047;
                    bf16x4 st;
#pragma unroll
                    for (int r2 = 0; r2 < 4; r2++) st[r2] = (bf16)acc[m][n][r2];
                    *(bf16x4*)((bf16*)Cout + 2 * MDc +
                               (size_t)((bb * H_ + head) * DH_ + dh) * N_ + nn) = st;
                } else {
                    bf16* dst = (bf16*)Cout + (size_t)slice * MDc;
#pragma unroll
                    for (int r2 = 0; r2 < 4; r2++) {
                        const int row = m0 + wr * 64 + m * 16 + lg * 4 + r2;
                        dst[(size_t)row * D_ + c] = (bf16)acc[m][n][r2];
                    }
                }
            } else {
#pragma unroll
                for (int r2 = 0; r2 < 4; r2++) {
                    const int row = m0 + wr * 64 + m * 16 + lg * 4 + r2;
                    float v = acc[m][n][r2] + bv;
                    if (EPI == 1 || EPI == 3) v += res[(size_t)row * N + col];
                    if (EPI == 2) v = 0.5f * v * (1.0f + erff(v * 0.70710678118654752f));
                    if (OMODE == 1) ((bf16*)Cout)[(size_t)row * N + col] = (bf16)v;
                    else            ((float*)Cout)[(size_t)row * N + col] = v;
                }
            }
        }
}

// ---------------------------------------------------------------------------
// bf16 MFMA flash attention, swapped-QK^T per-lane softmax.
// grid (N/128, H, B), 512 threads = 8 waves; wave owns 16 q-rows (q = q0w+lr).
// S^T = mfma(K_frag, Q_frag): lane holds S[kv=ni*16+lg*4+r2][q=lr] ->
// softmax state (m,l,resc) is per-lane scalar; row-reduce = 15 reg-ops +
// 2 shfl_xor (16,32). P packed as bf16x2 -> per-wave LDS [q][kv] (8 u32
// writes), reread as B-frag (2 ds_read_b128). PV: O^T = mfma(V^T, P^T).
// K/V double-buffered, staged via global_load_lds with pre-swizzled source
// chunk c^(r&7); NO 1/sqrt(d) scaling (per reference).
// ---------------------------------------------------------------------------
__global__ __launch_bounds__(512, 4) void mfma_attn(const bf16* __restrict__ Q,
                                                    const bf16* __restrict__ K,
                                                    const bf16* __restrict__ Vt,
                                                    bf16* __restrict__ O)
{
    const int qt = blockIdx.x, h = blockIdx.y, b = blockIdx.z;
    const int t = threadIdx.x, w = t >> 6, lane = t & 63;
    const int lr = lane & 15, lg = lane >> 4;

    __shared__ bf16 Ks[2][64 * 64];   // [buf][kv][dh] swizzled
    __shared__ bf16 Vs[2][64 * 64];   // [buf][dh][kv] swizzled
    __shared__ bf16 Ps[8][16 * 72];   // per-wave P^T as [q][kv], row stride 72

    const int q0w = qt * 128 + w * 16;
    // Q as B-operand fragments: B[k=dh][col=q=lr]
    bf16x8 b_q[2];
#pragma unroll
    for (int ki = 0; ki < 2; ki++)
        b_q[ki] = *(const bf16x8*)&Q[(size_t)(b * N_ + q0w + lr) * (H_ * DH_)
                                     + h * DH_ + ki * 32 + lg * 8];

    f32x4 acc[4];                      // O^T[d = nd*16+lg*4+r2][q=lr]
#pragma unroll
    for (int nd = 0; nd < 4; nd++) acc[nd] = {0.f, 0.f, 0.f, 0.f};
    float m_run = -3.0e38f, l_run = 0.f;

    // staging: each thread does ONE 16B copy per matrix; row r = w*8+(lane>>3)
    const int srow = lane >> 3;               // 0..7
    const int schunk = (lane & 7) ^ srow;     // pre-swizzled source chunk
    const int r_st = w * 8 + srow;            // 0..63

    auto stage = [&](int kv0, int buf) {
        async_copy16(&K[(size_t)(b * N_ + kv0 + r_st) * (H_ * DH_) + h * DH_ + schunk * 8],
                     &Ks[buf][w * 8 * 64]);
        async_copy16(&Vt[((size_t)(b * H_ + h) * DH_ + r_st) * N_ + kv0 + schunk * 8],
                     &Vs[buf][w * 8 * 64]);
    };

    stage(0, 0);
    const int NT = N_ / 64;
    for (int it = 0; it < NT; ++it) {
        __syncthreads();                          // current buf staged
        if (it + 1 < NT) stage((it + 1) * 64, (it + 1) & 1);
        const bf16* ks = Ks[it & 1];
        const bf16* vs = Vs[it & 1];

        // ---- S^T = K Q : s[ni][r2] = S[kv=ni*16+lg*4+r2][q=lr] ----
        f32x4 s[4];
#pragma unroll
        for (int ni = 0; ni < 4; ni++) s[ni] = {0.f, 0.f, 0.f, 0.f};
        __builtin_amdgcn_s_setprio(1);
#pragma unroll
        for (int ki = 0; ki < 2; ki++)
#pragma unroll
            for (int ni = 0; ni < 4; ni++) {
                const int r = ni * 16 + lr;
                const int slot = (lg + ki * 4) ^ (r & 7);
                const bf16x8 bk = *(const bf16x8*)&ks[r * 64 + slot * 8];
                s[ni] = __builtin_amdgcn_mfma_f32_16x16x32_bf16(
                    bk, b_q[ki], s[ni], 0, 0, 0);
            }
        __builtin_amdgcn_s_setprio(0);

        // ---- per-lane online softmax (lane owns q = q0w+lr, 16 kv values) ----
        float pmax = s[0][0];
#pragma unroll
        for (int ni = 0; ni < 4; ni++)
#pragma unroll
            for (int r2 = 0; r2 < 4; r2++)
                pmax = fmaxf(pmax, s[ni][r2]);
        pmax = fmaxf(pmax, __shfl_xor(pmax, 16));
        pmax = fmaxf(pmax, __shfl_xor(pmax, 32));
        const float mn = fmaxf(m_run, pmax);
        const float resc = __expf(m_run - mn);
        m_run = mn;

        float p[4][4];
        float rsum = 0.f;
#pragma unroll
        for (int ni = 0; ni < 4; ni++)
#pragma unroll
            for (int r2 = 0; r2 < 4; r2++) {
                p[ni][r2] = __expf(s[ni][r2] - mn);
                rsum += p[ni][r2];
            }
        rsum += __shfl_xor(rsum, 16);
        rsum += __shfl_xor(rsum, 32);
        l_run = l_run * resc + rsum;
#pragma unroll
        for (int nd = 0; nd < 4; nd++)
#pragma unroll
            for (int r2 = 0; r2 < 4; r2++) acc[nd][r2] *= resc;

        // ---- pack P -> Ps[w] as [q=lr][kv], bf16x2 (u32) writes ----
#pragma unroll
        for (int ni = 0; ni < 4; ni++)
#pragma unroll
            for (int hh = 0; hh < 2; hh++) {
                bf16x2 pr;
                pr[0] = (bf16)p[ni][2 * hh + 0];
                pr[1] = (bf16)p[ni][2 * hh + 1];
                *(bf16x2*)&Ps[w][lr * 72 + ni * 16 + lg * 4 + hh * 2] = pr;
            }

        // ---- O^T += V^T P^T ----
        __builtin_amdgcn_s_setprio(1);
#pragma unroll
        for (int k2 = 0; k2 < 2; k2++) {
            const bf16x8 bp = *(const bf16x8*)&Ps[w][lr * 72 + k2 * 32 + lg * 8];
#pragma unroll
            for (int nd = 0; nd < 4; nd++) {
                const int r = nd * 16 + lr;
                const int slot = (lg + k2 * 4) ^ (r & 7);
                const bf16x8 av = *(const bf16x8*)&vs[r * 64 + slot * 8];
                acc[nd] = __builtin_amdgcn_mfma_f32_16x16x32_bf16(
                    av, bp, acc[nd], 0, 0, 0);
            }
        }
        __builtin_amdgcn_s_setprio(0);
    }

    // ---- epilogue: O[q][d] = O^T / l ; 4x bf16x4 stores (d-contiguous) ----
    const float inv = 1.f / l_run;
    const size_t obase = (size_t)(b * N_ + q0w + lr) * (H_ * DH_) + h * DH_;
#pragma unroll
    for (int nd = 0; nd < 4; nd++) {
        bf16x4 o4;
#pragma unroll
        for (int r2 = 0; r2 < 4; r2++) o4[r2] = (bf16)(acc[nd][r2] * inv);
        *(bf16x4*)&O[obase + nd * 16 + lg * 4] = o4;
    }
}

// ---------------------------------------------------------------------------
extern "C" void kernel_launch(void* const* d_in, const int* in_sizes, int n_in,
                              void* d_out, int out_size, void* d_ws, size_t ws_size,
                              hipStream_t stream)
{
    const float* x     = (const float*)d_in[0];
    const float* wq    = (const float*)d_in[1];
    const float* wk    = (const float*)d_in[2];
    const float* wv    = (const float*)d_in[3];
    const float* wo    = (const float*)d_in[4];
    const float* w1    = (const float*)d_in[5];
    const float* b1    = (const float*)d_in[6];
    const float* w2    = (const float*)d_in[7];
    const float* b2    = (const float*)d_in[8];
    const float* ln1_g = (const float*)d_in[9];
    const float* ln1_b = (const float*)d_in[10];
    const float* ln2_g = (const float*)d_in[11];
    const float* ln2_b = (const float*)d_in[12];

    const size_t MD = (size_t)M_ * D_;
    char* wsb = (char*)d_ws;
    auto alloc = [&](size_t bytes) { char* p = wsb; wsb += (bytes + 255) & ~(size_t)255; return p; };
    bf16*  hb    = (bf16*)alloc(MD * 2);               // LN1 out
    bf16*  qb    = (bf16*)alloc(MD * 2 * 3);           // Q | K | V^T contiguous
    bf16*  kb    = qb + MD;
    bf16*  vtb   = qb + 2 * MD;
    bf16*  ab    = (bf16*)alloc(MD * 2);               // attn out
    float* x1    = (float*)alloc(MD * 4);              // residual after attn
    bf16*  h2b   = (bf16*)alloc(MD * 2);               // LN2 out
    bf16*  ffb   = (bf16*)alloc((size_t)M_ * FF_ * 2); // GELU out
    bf16*  wqkvT = (bf16*)alloc((size_t)3 * D_ * D_ * 2);
    bf16*  woT   = (bf16*)alloc((size_t)D_ * D_ * 2);
    bf16*  w1T   = (bf16*)alloc((size_t)D_ * FF_ * 2);
    bf16*  w2T   = (bf16*)alloc((size_t)FF_ * D_ * 2);

    dim3 tb(32, 8);
    transpose3_bf16<<<dim3(D_ / 32, D_ / 32, 3), tb, 0, stream>>>(wq, wk, wv, wqkvT);
    transpose_bf16<<<dim3(D_ / 32, D_ / 32), tb, 0, stream>>>(wo, woT, D_, D_);
    transpose_bf16<<<dim3(FF_ / 32, D_ / 32), tb, 0, stream>>>(w1, w1T, D_, FF_);
    transpose_bf16<<<dim3(D_ / 32, FF_ / 32), tb, 0, stream>>>(w2, w2T, FF_, D_);

    // 1. LN1
    ln_kernel<<<M_, 256, 0, stream>>>(x, ln1_g, ln1_b, hb);

    // 2. fused QKV projection (N=3072; epilogue routes Q/K/V^T)
    mfma_gemm<0, 3><<<dim3(3 * D_ / 128, M_ / 128), 256, 0, stream>>>(
        hb, wqkvT, qb, M_, 3 * D_, D_, nullptr, nullptr);

    // 3. MFMA flash attention (swapped QK^T, per-lane softmax, 8 waves)
    mfma_attn<<<dim3(N_ / 128, H_, B_), 512, 0, stream>>>(qb, kb, vtb, ab);

    // 4. x1 = attn @ wo + x
    dim3 gP(D_ / 128, M_ / 128);
    mfma_gemm<1, 0><<<gP, 256, 0, stream>>>(ab, woT, x1, M_, D_, D_, nullptr, x);

    // 5. LN2
    ln_kernel<<<M_, 256, 0, stream>>>(x1, ln2_g, ln2_b, h2b);

    // 6. ff = GELU(h2 @ w1 + b1)
    mfma_gemm<2, 1><<<dim3(FF_ / 128, M_ / 128), 256, 0, stream>>>(
        h2b, w1T, ffb, M_, FF_, D_, b1, nullptr);

    // 7. out = ff @ w2 + b2 + x1
    mfma_gemm<3, 0><<<dim3(D_ / 128, M_ / 128), 256, 0, stream>>>(
        ffb, w2T, (float*)d_out, M_, D_, FF_, b2, x1);
}

// Round 9
// 407.506 us; speedup vs baseline: 6.8669x; 1.0324x over previous
//
#include <hip/hip_runtime.h>
#include <math.h>
#include <stdint.h>

#define B_  2
#define N_  2048
#define D_  1024
#define H_  16
#define DH_ 64
#define FF_ 4096
#define M_  (B_ * N_)   // 4096 rows total

typedef __bf16 bf16;
typedef float  f32x4  __attribute__((ext_vector_type(4)));
typedef __bf16 bf16x8 __attribute__((ext_vector_type(8)));
typedef __bf16 bf16x4 __attribute__((ext_vector_type(4)));
typedef __bf16 bf16x2 __attribute__((ext_vector_type(2)));

// async global->LDS, 16B per lane; LDS dest = wave-uniform base + lane*16
__device__ __forceinline__ void async_copy16(const void* g, void* l) {
    __builtin_amdgcn_global_load_lds((__attribute__((address_space(1))) unsigned int*)g,
                                     (__attribute__((address_space(3))) unsigned int*)l,
                                     16, 0, 0);
}

// ---------------------------------------------------------------------------
// LayerNorm: one block per row, 256 threads, D=1024. fp32 in, bf16 out.
// ---------------------------------------------------------------------------
__global__ __launch_bounds__(256) void ln_kernel(const float* __restrict__ x,
                                                 const float* __restrict__ g,
                                                 const float* __restrict__ bta,
                                                 bf16* __restrict__ y)
{
    const int row = blockIdx.x;
    const int t = threadIdx.x;
    const float4 v = ((const float4*)(x + (size_t)row * D_))[t];
    float s  = v.x + v.y + v.z + v.w;
    float s2 = v.x * v.x + v.y * v.y + v.z * v.z + v.w * v.w;
#pragma unroll
    for (int o = 32; o > 0; o >>= 1) {
        s  += __shfl_down(s, o);
        s2 += __shfl_down(s2, o);
    }
    __shared__ float red[8];
    const int wid = t >> 6;
    if ((t & 63) == 0) { red[wid] = s; red[4 + wid] = s2; }
    __syncthreads();
    if (t == 0) {
        red[0] = red[0] + red[1] + red[2] + red[3];
        red[4] = red[4] + red[5] + red[6] + red[7];
    }
    __syncthreads();
    const float mean = red[0] * (1.0f / D_);
    const float var  = red[4] * (1.0f / D_) - mean * mean;
    const float rstd = rsqrtf(var + 1e-5f);
    const float4 gg = ((const float4*)g)[t];
    const float4 bb = ((const float4*)bta)[t];
    bf16x4 o;
    o[0] = (bf16)((v.x - mean) * rstd * gg.x + bb.x);
    o[1] = (bf16)((v.y - mean) * rstd * gg.y + bb.y);
    o[2] = (bf16)((v.z - mean) * rstd * gg.z + bb.z);
    o[3] = (bf16)((v.w - mean) * rstd * gg.w + bb.w);
    ((bf16x4*)(y + (size_t)row * D_))[t] = o;
}

// ---------------------------------------------------------------------------
// fp32 [R][C] -> bf16 [C][R] transpose (weights, once per launch).
// ---------------------------------------------------------------------------
__global__ __launch_bounds__(256) void transpose_bf16(const float* __restrict__ in,
                                                      bf16* __restrict__ out,
                                                      int R, int C)
{
    __shared__ float tile[32][33];
    const int c0 = blockIdx.x * 32, r0 = blockIdx.y * 32;
    const int tx = threadIdx.x, ty = threadIdx.y;  // (32,8)
#pragma unroll
    for (int i = 0; i < 4; i++)
        tile[ty + i * 8][tx] = in[(size_t)(r0 + ty + i * 8) * C + c0 + tx];
    __syncthreads();
#pragma unroll
    for (int i = 0; i < 4; i++)
        out[(size_t)(c0 + ty + i * 8) * R + r0 + tx] = (bf16)tile[tx][ty + i * 8];
}

// 3 D_xD_ sources -> one [3*D_][D_] bf16 transposed buffer (z = which source)
__global__ __launch_bounds__(256) void transpose3_bf16(const float* __restrict__ a,
                                                       const float* __restrict__ b,
                                                       const float* __restrict__ c,
                                                       bf16* __restrict__ out)
{
    __shared__ float tile[32][33];
    const float* in = (blockIdx.z == 0) ? a : (blockIdx.z == 1) ? b : c;
    bf16* o = out + (size_t)blockIdx.z * D_ * D_;
    const int c0 = blockIdx.x * 32, r0 = blockIdx.y * 32;
    const int tx = threadIdx.x, ty = threadIdx.y;  // (32,8)
#pragma unroll
    for (int i = 0; i < 4; i++)
        tile[ty + i * 8][tx] = in[(size_t)(r0 + ty + i * 8) * D_ + c0 + tx];
    __syncthreads();
#pragma unroll
    for (int i = 0; i < 4; i++)
        o[(size_t)(c0 + ty + i * 8) * D_ + r0 + tx] = (bf16)tile[tx][ty + i * 8];
}

// ---------------------------------------------------------------------------
// bf16 MFMA GEMM (m97 structure): C(MxN) = A(MxK) @ Bt(NxK)^T
// Bijective XCD swizzle on the (x,y) grid (nwg % 8 == 0 for all our shapes).
// Split-K via blockIdx.z: each z computes k in [z*kspl, (z+1)*kspl).
// EPI: 0 none | 1 +res | 2 +bias,GELU | 3 +bias,+res
// OMODE: 0 f32 | 1 bf16 | 3 fused-QKV routing | 4 f32 partial (+z*M*N), no epi
// ---------------------------------------------------------------------------
template <int EPI, int OMODE>
__global__ __launch_bounds__(256) void mfma_gemm(const bf16* __restrict__ A,
                                                 const bf16* __restrict__ Bt,
                                                 void* __restrict__ Cout,
                                                 int M, int N, int K, int kspl,
                                                 const float* __restrict__ bias,
                                                 const float* __restrict__ res)
{
    __shared__ bf16 As[128 * 32];
    __shared__ bf16 Bs[128 * 32];
    const int t = threadIdx.x;
    const int w = t >> 6, lane = t & 63;
    const int wr = w >> 1, wc = w & 1;

    // XCD-aware swizzle: consecutive swizzled ids land on one XCD's L2
    const unsigned nwg = gridDim.x * gridDim.y;
    const unsigned lid = blockIdx.y * gridDim.x + blockIdx.x;
    const unsigned q = nwg >> 3;                     // nwg % 8 == 0 guaranteed
    const unsigned swz = (lid & 7) * q + (lid >> 3);
    const int bx = swz % gridDim.x, by = swz / gridDim.x;
    const int ks = blockIdx.z;

    const int m0 = by * 128, n0 = bx * 128;
    const int lr = lane & 15, lg = lane >> 4;
    const size_t MDc = (size_t)M_ * D_;

    f32x4 acc[4][4];
#pragma unroll
    for (int m = 0; m < 4; m++)
#pragma unroll
        for (int n = 0; n < 4; n++) acc[m][n] = {0.f, 0.f, 0.f, 0.f};

    const int q0c = w * 2, q1c = w * 2 + 1;
    const int row0 = q0c * 16 + (lane >> 2);
    const int row1 = q1c * 16 + (lane >> 2);
    const int kk = (lane & 3) * 8;

    const int kbeg = ks * kspl, kend = kbeg + kspl;
    for (int k0 = kbeg; k0 < kend; k0 += 32) {
        async_copy16(A  + (size_t)(m0 + row0) * K + k0 + kk, &As[q0c * 512]);
        async_copy16(A  + (size_t)(m0 + row1) * K + k0 + kk, &As[q1c * 512]);
        async_copy16(Bt + (size_t)(n0 + row0) * K + k0 + kk, &Bs[q0c * 512]);
        async_copy16(Bt + (size_t)(n0 + row1) * K + k0 + kk, &Bs[q1c * 512]);
        __syncthreads();

        bf16x8 af[4], bfr[4];
#pragma unroll
        for (int m = 0; m < 4; m++)
            af[m] = *(const bf16x8*)&As[(wr * 64 + m * 16 + lr) * 32 + lg * 8];
#pragma unroll
        for (int n = 0; n < 4; n++)
            bfr[n] = *(const bf16x8*)&Bs[(wc * 64 + n * 16 + lr) * 32 + lg * 8];
#pragma unroll
        for (int m = 0; m < 4; m++)
#pragma unroll
            for (int n = 0; n < 4; n++)
                acc[m][n] = __builtin_amdgcn_mfma_f32_16x16x32_bf16(
                    af[m], bfr[n], acc[m][n], 0, 0, 0);
        __syncthreads();
    }

#pragma unroll
    for (int m = 0; m < 4; m++)
#pragma unroll
        for (int n = 0; n < 4; n++) {
            const int col = n0 + wc * 64 + n * 16 + lr;
            const float bv = (EPI >= 2 && OMODE != 4) ? bias[col] : 0.f;
            if (OMODE == 4) {
                float* dst = (float*)Cout + (size_t)ks * M * N;
#pragma unroll
                for (int r2 = 0; r2 < 4; r2++) {
                    const int row = m0 + wr * 64 + m * 16 + lg * 4 + r2;
                    dst[(size_t)row * N + col] = acc[m][n][r2];
                }
            } else if (OMODE == 3) {
                const int slice = col >> 10;       // 0=Q 1=K 2=V (uniform per frag)
                const int c = col & 1023;
                if (slice == 2) {
                    const int head = c >> 6, dh = c & 63;
                    const int row0_ = m0 + wr * 64 + m * 16 + lg * 4;
                    const int bb = row0_ >> 11, nn = row0_ & 2047;
                    bf16x4 st;
#pragma unroll
                    for (int r2 = 0; r2 < 4; r2++) st[r2] = (bf16)acc[m][n][r2];
                    *(bf16x4*)((bf16*)Cout + 2 * MDc +
                               (size_t)((bb * H_ + head) * DH_ + dh) * N_ + nn) = st;
                } else {
                    bf16* dst = (bf16*)Cout + (size_t)slice * MDc;
#pragma unroll
                    for (int r2 = 0; r2 < 4; r2++) {
                        const int row = m0 + wr * 64 + m * 16 + lg * 4 + r2;
                        dst[(size_t)row * D_ + c] = (bf16)acc[m][n][r2];
                    }
                }
            } else {
#pragma unroll
                for (int r2 = 0; r2 < 4; r2++) {
                    const int row = m0 + wr * 64 + m * 16 + lg * 4 + r2;
                    float v = acc[m][n][r2] + bv;
                    if (EPI == 1 || EPI == 3) v += res[(size_t)row * N + col];
                    if (EPI == 2) v = 0.5f * v * (1.0f + erff(v * 0.70710678118654752f));
                    if (OMODE == 1) ((bf16*)Cout)[(size_t)row * N + col] = (bf16)v;
                    else            ((float*)Cout)[(size_t)row * N + col] = v;
                }
            }
        }
}

// out = part0 + part1 + bias(col) + res   (FF2 split-K reduce; f32, float4)
__global__ __launch_bounds__(256) void reduce2_kernel(const float* __restrict__ p0,
                                                      const float* __restrict__ p1,
                                                      const float* __restrict__ bias,
                                                      const float* __restrict__ res,
                                                      float* __restrict__ out)
{
    const size_t idx = ((size_t)blockIdx.x * 256 + threadIdx.x) * 4;
    const float4 a = *(const float4*)(p0 + idx);
    const float4 b = *(const float4*)(p1 + idx);
    const float4 r = *(const float4*)(res + idx);
    const float4 bb = *(const float4*)(bias + (idx & (D_ - 1)));
    float4 o;
    o.x = a.x + b.x + r.x + bb.x;
    o.y = a.y + b.y + r.y + bb.y;
    o.z = a.z + b.z + r.z + bb.z;
    o.w = a.w + b.w + r.w + bb.w;
    *(float4*)(out + idx) = o;
}

// ---------------------------------------------------------------------------
// bf16 MFMA flash attention, swapped-QK^T per-lane softmax (unchanged, R8-pass).
// ---------------------------------------------------------------------------
__global__ __launch_bounds__(512, 4) void mfma_attn(const bf16* __restrict__ Q,
                                                    const bf16* __restrict__ K,
                                                    const bf16* __restrict__ Vt,
                                                    bf16* __restrict__ O)
{
    const int qt = blockIdx.x, h = blockIdx.y, b = blockIdx.z;
    const int t = threadIdx.x, w = t >> 6, lane = t & 63;
    const int lr = lane & 15, lg = lane >> 4;

    __shared__ bf16 Ks[2][64 * 64];   // [buf][kv][dh] swizzled
    __shared__ bf16 Vs[2][64 * 64];   // [buf][dh][kv] swizzled
    __shared__ bf16 Ps[8][16 * 72];   // per-wave P^T as [q][kv], row stride 72

    const int q0w = qt * 128 + w * 16;
    bf16x8 b_q[2];
#pragma unroll
    for (int ki = 0; ki < 2; ki++)
        b_q[ki] = *(const bf16x8*)&Q[(size_t)(b * N_ + q0w + lr) * (H_ * DH_)
                                     + h * DH_ + ki * 32 + lg * 8];

    f32x4 acc[4];                      // O^T[d = nd*16+lg*4+r2][q=lr]
#pragma unroll
    for (int nd = 0; nd < 4; nd++) acc[nd] = {0.f, 0.f, 0.f, 0.f};
    float m_run = -3.0e38f, l_run = 0.f;

    const int srow = lane >> 3;               // 0..7
    const int schunk = (lane & 7) ^ srow;     // pre-swizzled source chunk
    const int r_st = w * 8 + srow;            // 0..63

    auto stage = [&](int kv0, int buf) {
        async_copy16(&K[(size_t)(b * N_ + kv0 + r_st) * (H_ * DH_) + h * DH_ + schunk * 8],
                     &Ks[buf][w * 8 * 64]);
        async_copy16(&Vt[((size_t)(b * H_ + h) * DH_ + r_st) * N_ + kv0 + schunk * 8],
                     &Vs[buf][w * 8 * 64]);
    };

    stage(0, 0);
    const int NT = N_ / 64;
    for (int it = 0; it < NT; ++it) {
        __syncthreads();                          // current buf staged
        if (it + 1 < NT) stage((it + 1) * 64, (it + 1) & 1);
        const bf16* ks = Ks[it & 1];
        const bf16* vs = Vs[it & 1];

        // ---- S^T = K Q ----
        f32x4 s[4];
#pragma unroll
        for (int ni = 0; ni < 4; ni++) s[ni] = {0.f, 0.f, 0.f, 0.f};
        __builtin_amdgcn_s_setprio(1);
#pragma unroll
        for (int ki = 0; ki < 2; ki++)
#pragma unroll
            for (int ni = 0; ni < 4; ni++) {
                const int r = ni * 16 + lr;
                const int slot = (lg + ki * 4) ^ (r & 7);
                const bf16x8 bk = *(const bf16x8*)&ks[r * 64 + slot * 8];
                s[ni] = __builtin_amdgcn_mfma_f32_16x16x32_bf16(
                    bk, b_q[ki], s[ni], 0, 0, 0);
            }
        __builtin_amdgcn_s_setprio(0);

        // ---- per-lane online softmax ----
        float pmax = s[0][0];
#pragma unroll
        for (int ni = 0; ni < 4; ni++)
#pragma unroll
            for (int r2 = 0; r2 < 4; r2++)
                pmax = fmaxf(pmax, s[ni][r2]);
        pmax = fmaxf(pmax, __shfl_xor(pmax, 16));
        pmax = fmaxf(pmax, __shfl_xor(pmax, 32));
        const float mn = fmaxf(m_run, pmax);
        const float resc = __expf(m_run - mn);
        m_run = mn;

        float p[4][4];
        float rsum = 0.f;
#pragma unroll
        for (int ni = 0; ni < 4; ni++)
#pragma unroll
            for (int r2 = 0; r2 < 4; r2++) {
                p[ni][r2] = __expf(s[ni][r2] - mn);
                rsum += p[ni][r2];
            }
        rsum += __shfl_xor(rsum, 16);
        rsum += __shfl_xor(rsum, 32);
        l_run = l_run * resc + rsum;
#pragma unroll
        for (int nd = 0; nd < 4; nd++)
#pragma unroll
            for (int r2 = 0; r2 < 4; r2++) acc[nd][r2] *= resc;

        // ---- pack P -> Ps[w] as [q=lr][kv] ----
#pragma unroll
        for (int ni = 0; ni < 4; ni++)
#pragma unroll
            for (int hh = 0; hh < 2; hh++) {
                bf16x2 pr;
                pr[0] = (bf16)p[ni][2 * hh + 0];
                pr[1] = (bf16)p[ni][2 * hh + 1];
                *(bf16x2*)&Ps[w][lr * 72 + ni * 16 + lg * 4 + hh * 2] = pr;
            }

        // ---- O^T += V^T P^T ----
        __builtin_amdgcn_s_setprio(1);
#pragma unroll
        for (int k2 = 0; k2 < 2; k2++) {
            const bf16x8 bp = *(const bf16x8*)&Ps[w][lr * 72 + k2 * 32 + lg * 8];
#pragma unroll
            for (int nd = 0; nd < 4; nd++) {
                const int r = nd * 16 + lr;
                const int slot = (lg + k2 * 4) ^ (r & 7);
                const bf16x8 av = *(const bf16x8*)&vs[r * 64 + slot * 8];
                acc[nd] = __builtin_amdgcn_mfma_f32_16x16x32_bf16(
                    av, bp, acc[nd], 0, 0, 0);
            }
        }
        __builtin_amdgcn_s_setprio(0);
    }

    // ---- epilogue ----
    const float inv = 1.f / l_run;
    const size_t obase = (size_t)(b * N_ + q0w + lr) * (H_ * DH_) + h * DH_;
#pragma unroll
    for (int nd = 0; nd < 4; nd++) {
        bf16x4 o4;
#pragma unroll
        for (int r2 = 0; r2 < 4; r2++) o4[r2] = (bf16)(acc[nd][r2] * inv);
        *(bf16x4*)&O[obase + nd * 16 + lg * 4] = o4;
    }
}

// ---------------------------------------------------------------------------
extern "C" void kernel_launch(void* const* d_in, const int* in_sizes, int n_in,
                              void* d_out, int out_size, void* d_ws, size_t ws_size,
                              hipStream_t stream)
{
    const float* x     = (const float*)d_in[0];
    const float* wq    = (const float*)d_in[1];
    const float* wk    = (const float*)d_in[2];
    const float* wv    = (const float*)d_in[3];
    const float* wo    = (const float*)d_in[4];
    const float* w1    = (const float*)d_in[5];
    const float* b1    = (const float*)d_in[6];
    const float* w2    = (const float*)d_in[7];
    const float* b2    = (const float*)d_in[8];
    const float* ln1_g = (const float*)d_in[9];
    const float* ln1_b = (const float*)d_in[10];
    const float* ln2_g = (const float*)d_in[11];
    const float* ln2_b = (const float*)d_in[12];

    const size_t MD = (size_t)M_ * D_;
    char* wsb = (char*)d_ws;
    auto alloc = [&](size_t bytes) { char* p = wsb; wsb += (bytes + 255) & ~(size_t)255; return p; };
    bf16*  hb    = (bf16*)alloc(MD * 2);               // LN1 out
    bf16*  qb    = (bf16*)alloc(MD * 2 * 3);           // Q | K | V^T contiguous
    bf16*  kb    = qb + MD;
    bf16*  vtb   = qb + 2 * MD;
    bf16*  ab    = (bf16*)alloc(MD * 2);               // attn out
    float* x1    = (float*)alloc(MD * 4);              // residual after attn
    bf16*  h2b   = (bf16*)alloc(MD * 2);               // LN2 out
    bf16*  ffb   = (bf16*)alloc((size_t)M_ * FF_ * 2); // GELU out
    bf16*  wqkvT = (bf16*)alloc((size_t)3 * D_ * D_ * 2);
    bf16*  woT   = (bf16*)alloc((size_t)D_ * D_ * 2);
    bf16*  w1T   = (bf16*)alloc((size_t)D_ * FF_ * 2);
    bf16*  w2T   = (bf16*)alloc((size_t)FF_ * D_ * 2);
    // FF2 split-K partials: reuse hb+qkv region (dead by FF2), exactly 2*MD f32
    float* part0 = (float*)d_ws;
    float* part1 = part0 + MD;

    dim3 tb(32, 8);
    transpose3_bf16<<<dim3(D_ / 32, D_ / 32, 3), tb, 0, stream>>>(wq, wk, wv, wqkvT);
    transpose_bf16<<<dim3(D_ / 32, D_ / 32), tb, 0, stream>>>(wo, woT, D_, D_);
    transpose_bf16<<<dim3(FF_ / 32, D_ / 32), tb, 0, stream>>>(w1, w1T, D_, FF_);
    transpose_bf16<<<dim3(D_ / 32, FF_ / 32), tb, 0, stream>>>(w2, w2T, FF_, D_);

    // 1. LN1
    ln_kernel<<<M_, 256, 0, stream>>>(x, ln1_g, ln1_b, hb);

    // 2. fused QKV projection (N=3072; epilogue routes Q/K/V^T)
    mfma_gemm<0, 3><<<dim3(3 * D_ / 128, M_ / 128), 256, 0, stream>>>(
        hb, wqkvT, qb, M_, 3 * D_, D_, D_, nullptr, nullptr);

    // 3. MFMA flash attention (swapped QK^T, per-lane softmax, 8 waves)
    mfma_attn<<<dim3(N_ / 128, H_, B_), 512, 0, stream>>>(qb, kb, vtb, ab);

    // 4. x1 = attn @ wo + x
    dim3 gP(D_ / 128, M_ / 128);
    mfma_gemm<1, 0><<<gP, 256, 0, stream>>>(ab, woT, x1, M_, D_, D_, D_, nullptr, x);

    // 5. LN2
    ln_kernel<<<M_, 256, 0, stream>>>(x1, ln2_g, ln2_b, h2b);

    // 6. ff = GELU(h2 @ w1 + b1)
    mfma_gemm<2, 1><<<dim3(FF_ / 128, M_ / 128), 256, 0, stream>>>(
        h2b, w1T, ffb, M_, FF_, D_, D_, b1, nullptr);

    // 7. FF2 split-K=2: partials then fused reduce (+b2 +x1)
    mfma_gemm<0, 4><<<dim3(D_ / 128, M_ / 128, 2), 256, 0, stream>>>(
        ffb, w2T, part0, M_, D_, FF_, FF_ / 2, nullptr, nullptr);
    reduce2_kernel<<<MD / (256 * 4), 256, 0, stream>>>(
        part0, part1, b2, x1, (float*)d_out);
}